// Round 12
// baseline (442.272 us; speedup 1.0000x reference)
//
#include <hip/hip_runtime.h>
#include <math.h>

typedef _Float16 half8 __attribute__((ext_vector_type(8)));
typedef float f32x4 __attribute__((ext_vector_type(4)));

__device__ inline uint splitpack(float v) {
    _Float16 h = (_Float16)v;
    float r = v - (float)h;
    _Float16 l = (_Float16)r;
    return (uint)__builtin_bit_cast(unsigned short, h) |
           ((uint)__builtin_bit_cast(unsigned short, l) << 16);
}
__device__ inline _Float16 lo16h(uint u) { return __builtin_bit_cast(_Float16, (unsigned short)(u & 0xffffu)); }
__device__ inline _Float16 hi16h(uint u) { return __builtin_bit_cast(_Float16, (unsigned short)(u >> 16)); }
__device__ inline uint packhh(_Float16 a, _Float16 b) {
    return (uint)__builtin_bit_cast(unsigned short, a) |
           ((uint)__builtin_bit_cast(unsigned short, b) << 16);
}
__device__ inline float dpp_max8(float v) {
    int x = __builtin_amdgcn_mov_dpp(__builtin_bit_cast(int, v), 0x128, 0xf, 0xf, true);
    return fmaxf(v, __builtin_bit_cast(float, x));
}

// ---------------- fused conv1+conv2, 1 image/block: x:[N,3,32,32] -> p2:[N,400] fp32 ----------------
// LDS = 13.4K (simg) + 5.0K (p1l) + 64B -> 8 blocks/CU (occupancy VGPR-capped at 16 waves/CU).
// conv2 B-fragments per-lane from global (L1-cached) — no LDS staging.
__global__ __launch_bounds__(256) void k_conv12(const float* __restrict__ x,
                                                const float* __restrict__ w1,
                                                const float* __restrict__ b1,
                                                const float* __restrict__ w2,
                                                const float* __restrict__ b2,
                                                float* __restrict__ p2) {
    __shared__ uint simg[3360];    // 3 planes * 32 rows * 35 dw (13.4 KB)
    __shared__ uint p1l[1260];     // p1 in conv2 layout: [6][14x15] (5.0 KB)
    __shared__ float sb2[16];
    const int tid  = threadIdx.x;
    const int lane = tid & 63;
    const int wv   = tid >> 6;
    const int n0   = blockIdx.x;

    const int colb = lane & 15;
    const int c  = colb & 7, dx = colb >> 3;
    const int g  = lane >> 4;
    const int qr = g;

    // conv1 B fragments in registers
    half8 bh[3], bl[3];
    #pragma unroll
    for (int ks = 0; ks < 3; ++ks)
        #pragma unroll
        for (int jj = 0; jj < 8; ++jj) {
            int pi = jj >> 1, e = jj & 1;
            int rho = g * 4 + pi;
            float val = 0.f;
            if (rho < 15 && c < 6) {
                int ci = rho / 5, ky = rho % 5;
                int kx = ks * 2 + e - dx;
                if (kx >= 0 && kx < 5) val = w1[c * 75 + ci * 25 + ky * 5 + kx];
            }
            _Float16 hh = (_Float16)val;
            bh[ks][jj] = hh;
            bl[ks][jj] = (_Float16)(val - (float)hh);
        }
    const float bias1 = (c < 6) ? b1[c] : 0.f;

    // stage image (row-interleaved split-fp16)
    for (int i = tid; i < 768; i += 256) {
        int plane = i >> 8, rr = (i & 255) >> 3, f = i & 7;
        float4 v = *(const float4*)(x + ((size_t)n0 * 3 + plane) * 1024 + rr * 32 + f * 4);
        _Float16 h0 = (_Float16)v.x, h1 = (_Float16)v.y, h2 = (_Float16)v.z, h3 = (_Float16)v.w;
        _Float16 l0 = (_Float16)(v.x - (float)h0), l1 = (_Float16)(v.y - (float)h1);
        _Float16 l2 = (_Float16)(v.z - (float)h2), l3 = (_Float16)(v.w - (float)h3);
        int base = plane * 1120 + rr * 35 + f * 2;
        simg[base]      = packhh(h0, h1);
        simg[base + 1]  = packhh(h2, h3);
        simg[base + 16] = packhh(l0, l1);
        simg[base + 17] = packhh(l2, l3);
    }
    if (tid < 16) sb2[tid] = b2[tid];
    __syncthreads();

    // ---------------- conv1 main (round-10 structure, stores -> LDS) ----------------
    int poff[4];
    #pragma unroll
    for (int pi = 0; pi < 4; ++pi) {
        int rho = g * 4 + pi;
        if (rho > 14) rho = 14;
        poff[pi] = (rho / 5) * 1120 + (rho % 5) * 35;
    }

    for (int t0 = wv; t0 < 25; t0 += 8) {
        const int t1 = (t0 + 4 < 25) ? (t0 + 4) : t0;
        int r0c = t0 * 16 + colb; if (r0c > 391) r0c = 391;
        int r1c = t1 * 16 + colb; if (r1c > 391) r1c = 391;
        int qx0 = (r0c * 586) >> 14, yy0 = r0c - qx0 * 28;
        int qx1 = (r1c * 586) >> 14, yy1 = r1c - qx1 * 28;
        const uint* base0 = simg + yy0 * 35 + qx0;
        const uint* base1 = simg + yy1 * 35 + qx1;

        f32x4 A0[2] = {{0.f,0.f,0.f,0.f},{0.f,0.f,0.f,0.f}};
        f32x4 A1[2] = {{0.f,0.f,0.f,0.f},{0.f,0.f,0.f,0.f}};
        int c0 = 0, c1 = 0;
        #pragma unroll
        for (int ks = 0; ks < 3; ++ks) {
            uint h0[4], l0[4], h1[4], l1[4];
            #pragma unroll
            for (int pi = 0; pi < 4; ++pi) {
                const uint* a0p = base0 + poff[pi];
                const uint* a1p = base1 + poff[pi];
                h0[pi] = a0p[ks];  l0[pi] = a0p[16 + ks];   // ds_read2_b32 pairs
                h1[pi] = a1p[ks];  l1[pi] = a1p[16 + ks];
            }
            uint4 hv0; hv0.x = h0[0]; hv0.y = h0[1]; hv0.z = h0[2]; hv0.w = h0[3];
            uint4 lv0; lv0.x = l0[0]; lv0.y = l0[1]; lv0.z = l0[2]; lv0.w = l0[3];
            uint4 hv1; hv1.x = h1[0]; hv1.y = h1[1]; hv1.z = h1[2]; hv1.w = h1[3];
            uint4 lv1; lv1.x = l1[0]; lv1.y = l1[1]; lv1.z = l1[2]; lv1.w = l1[3];
            half8 ah0 = __builtin_bit_cast(half8, hv0);
            half8 al0 = __builtin_bit_cast(half8, lv0);
            half8 ah1 = __builtin_bit_cast(half8, hv1);
            half8 al1 = __builtin_bit_cast(half8, lv1);
            A0[c0 & 1] = __builtin_amdgcn_mfma_f32_16x16x32_f16(ah0, bh[ks], A0[c0 & 1], 0, 0, 0); ++c0;
            A1[c1 & 1] = __builtin_amdgcn_mfma_f32_16x16x32_f16(ah1, bh[ks], A1[c1 & 1], 0, 0, 0); ++c1;
            A0[c0 & 1] = __builtin_amdgcn_mfma_f32_16x16x32_f16(ah0, bl[ks], A0[c0 & 1], 0, 0, 0); ++c0;
            A1[c1 & 1] = __builtin_amdgcn_mfma_f32_16x16x32_f16(ah1, bl[ks], A1[c1 & 1], 0, 0, 0); ++c1;
            A0[c0 & 1] = __builtin_amdgcn_mfma_f32_16x16x32_f16(al0, bh[ks], A0[c0 & 1], 0, 0, 0); ++c0;
            A1[c1 & 1] = __builtin_amdgcn_mfma_f32_16x16x32_f16(al1, bh[ks], A1[c1 & 1], 0, 0, 0); ++c1;
        }
        {
            f32x4 acc;
            #pragma unroll
            for (int i = 0; i < 4; ++i) acc[i] = A0[0][i] + A0[1][i];
            float p01 = dpp_max8(fmaxf(acc[0], acc[1]));
            float p23 = dpp_max8(fmaxf(acc[2], acc[3]));
            if (dx == 0 && c < 6) {
                uint* outb = p1l + c * 210;
                int r0 = t0 * 16 + qr * 4;
                if (r0 + 1 < 392) {
                    int qxa = (r0 * 586) >> 14, ya = r0 - qxa * 28;
                    outb[(ya >> 1) * 15 + qxa] = splitpack(fmaxf(p01 + bias1, 0.f));
                }
                int r2 = r0 + 2;
                if (r2 + 1 < 392) {
                    int qxb = (r2 * 586) >> 14, yb = r2 - qxb * 28;
                    outb[(yb >> 1) * 15 + qxb] = splitpack(fmaxf(p23 + bias1, 0.f));
                }
            }
        }
        if (t1 != t0) {
            f32x4 acc;
            #pragma unroll
            for (int i = 0; i < 4; ++i) acc[i] = A1[0][i] + A1[1][i];
            float p01 = dpp_max8(fmaxf(acc[0], acc[1]));
            float p23 = dpp_max8(fmaxf(acc[2], acc[3]));
            if (dx == 0 && c < 6) {
                uint* outb = p1l + c * 210;
                int r0 = t1 * 16 + qr * 4;
                if (r0 + 1 < 392) {
                    int qxa = (r0 * 586) >> 14, ya = r0 - qxa * 28;
                    outb[(ya >> 1) * 15 + qxa] = splitpack(fmaxf(p01 + bias1, 0.f));
                }
                int r2 = r0 + 2;
                if (r2 + 1 < 392) {
                    int qxb = (r2 * 586) >> 14, yb = r2 - qxb * 28;
                    outb[(yb >> 1) * 15 + qxb] = splitpack(fmaxf(p23 + bias1, 0.f));
                }
            }
        }
    }
    __syncthreads();

    // ---------------- conv2 main (B-fragments per-lane from global; reads p1l) ----------------
    const int qw2 = (lane & 15) >> 2;
    const int dy2 = (lane >> 1) & 1, dxx2 = lane & 1;
    const int cc = lane & 15;
    int offs2[40];
    #pragma unroll
    for (int ks = 0; ks < 5; ++ks)
        #pragma unroll
        for (int j = 0; j < 8; ++j) {
            int k = ks * 32 + g * 8 + j;
            int o = 0;
            if (k < 150) { int ci = k / 25, r = k % 25; o = ci * 210 + (r / 5) * 15 + (r % 5); }
            offs2[ks * 8 + j] = o;
        }
    half8 bh2[5], bl2[5];
    #pragma unroll
    for (int ks = 0; ks < 5; ++ks)
        #pragma unroll
        for (int j = 0; j < 8; ++j) {
            int k = ks * 32 + g * 8 + j;
            float val = (k < 150) ? w2[cc * 150 + k] : 0.f;
            _Float16 hh = (_Float16)val;
            bh2[ks][j] = hh;
            bl2[ks][j] = (_Float16)(val - (float)hh);
        }
    const float bias2 = sb2[cc];

    for (int t = wv; t < 7; t += 4) {
        int qa = t * 4 + qw2; if (qa > 24) qa = 24;
        int qy = qa / 5, qx = qa % 5;
        int base = (2 * qy + dy2) * 15 + (2 * qx + dxx2);
        f32x4 acc2[2] = {{0.f,0.f,0.f,0.f},{0.f,0.f,0.f,0.f}};
        int pp = 0;
        #pragma unroll
        for (int ks = 0; ks < 5; ++ks) {
            uint up[8];
            #pragma unroll
            for (int j = 0; j < 8; ++j) up[j] = p1l[base + offs2[ks * 8 + j]];
            half8 ah, al;
            #pragma unroll
            for (int j = 0; j < 8; ++j) { ah[j] = lo16h(up[j]); al[j] = hi16h(up[j]); }
            acc2[pp & 1] = __builtin_amdgcn_mfma_f32_16x16x32_f16(ah, bh2[ks], acc2[pp & 1], 0, 0, 0); ++pp;
            acc2[pp & 1] = __builtin_amdgcn_mfma_f32_16x16x32_f16(ah, bl2[ks], acc2[pp & 1], 0, 0, 0); ++pp;
            acc2[pp & 1] = __builtin_amdgcn_mfma_f32_16x16x32_f16(al, bh2[ks], acc2[pp & 1], 0, 0, 0); ++pp;
        }
        int qc = t * 4 + qr;
        if (qc < 25) {
            float m = fmaxf(fmaxf(acc2[0][0] + acc2[1][0], acc2[0][1] + acc2[1][1]),
                            fmaxf(acc2[0][2] + acc2[1][2], acc2[0][3] + acc2[1][3]));
            p2[(size_t)n0 * 400 + cc * 25 + qc] = fmaxf(m + bias2, 0.f);
        }
    }
}

// ---------------- fc1: [N,400] @ [120,400]^T + relu -> h1:[N,120] ----------------
__global__ __launch_bounds__(256) void k_fc1(const float* __restrict__ p2,
                                             const float* __restrict__ w,
                                             const float* __restrict__ b,
                                             float* __restrict__ h1) {
    __shared__ float sa[64 * 100];
    __shared__ float swt[120 * 101];
    const int tid = threadIdx.x;
    const int n0 = blockIdx.x * 64;
    const int tc = tid % 30, tr = tid / 30;
    float acc[8][4];
    #pragma unroll
    for (int i = 0; i < 8; ++i)
        #pragma unroll
        for (int j = 0; j < 4; ++j) acc[i][j] = 0.f;

    for (int kt = 0; kt < 4; ++kt) {
        __syncthreads();
        for (int i = tid; i < 1600; i += 256) {
            int r = i / 25, k4 = (i % 25) * 4;
            float4 v = *(const float4*)(p2 + (size_t)(n0 + r) * 400 + kt * 100 + k4);
            *(float4*)(sa + r * 100 + k4) = v;
        }
        for (int i = tid; i < 3000; i += 256) {
            int c = i / 25, k4 = (i % 25) * 4;
            float4 v = *(const float4*)(w + (size_t)c * 400 + kt * 100 + k4);
            float* d = swt + c * 101 + k4;
            d[0] = v.x; d[1] = v.y; d[2] = v.z; d[3] = v.w;
        }
        __syncthreads();
        if (tr < 8) {
            #pragma unroll 4
            for (int k = 0; k < 100; ++k) {
                float av[8], wv[4];
                #pragma unroll
                for (int i = 0; i < 8; ++i) av[i] = sa[(tr * 8 + i) * 100 + k];
                #pragma unroll
                for (int j = 0; j < 4; ++j) wv[j] = swt[(tc * 4 + j) * 101 + k];
                #pragma unroll
                for (int i = 0; i < 8; ++i)
                    #pragma unroll
                    for (int j = 0; j < 4; ++j) acc[i][j] = fmaf(av[i], wv[j], acc[i][j]);
            }
        }
    }
    if (tr < 8) {
        #pragma unroll
        for (int j = 0; j < 4; ++j) {
            const int o = tc * 4 + j;
            const float bo = b[o];
            #pragma unroll
            for (int i = 0; i < 8; ++i) {
                const int rr = n0 + tr * 8 + i;
                h1[(size_t)rr * 120 + o] = fmaxf(acc[i][j] + bo, 0.f);
            }
        }
    }
}

// ---------------- compose: C[e][o][d] = sum_j head_w[o][j]*expert_w[e][j][d] ----------------
__global__ __launch_bounds__(256) void k_compose(const float* __restrict__ ew,
                                                 const float* __restrict__ eb,
                                                 const float* __restrict__ hw,
                                                 float* __restrict__ C,
                                                 float* __restrict__ hb2) {
    __shared__ float shw[840];
    __shared__ float seb[672];
    const int e = blockIdx.x, tid = threadIdx.x;
    for (int i = tid; i < 840; i += 256) shw[i] = hw[i];
    for (int i = tid; i < 672; i += 256) seb[i] = eb[i];
    __syncthreads();
    for (int i = tid; i < 840; i += 256) {
        int o = i / 84, d = i % 84;
        float s = 0.f;
        for (int j = 0; j < 84; ++j)
            s = fmaf(shw[o * 84 + j], ew[((size_t)e * 84 + j) * 84 + d], s);
        C[e * 840 + i] = s;
    }
    if (tid < 10) {
        float s = 0.f;
        for (int j = 0; j < 84; ++j) s = fmaf(shw[tid * 84 + j], seb[e * 84 + j], s);
        hb2[e * 10 + tid] = s;
    }
}

// ---------------- tail: fc2+relu, gate, top2-softmax, MoE(composed)+head ----------------
__global__ __launch_bounds__(256) void k_tail(const float* __restrict__ h1,
                                              const float* __restrict__ f2w,
                                              const float* __restrict__ f2b,
                                              const float* __restrict__ gw,
                                              const float* __restrict__ Cw,
                                              const float* __restrict__ hb2,
                                              const float* __restrict__ headb,
                                              float* __restrict__ out) {
    __shared__ float sh1[64 * 120];
    __shared__ float sfw[84 * 121];
    __shared__ float sfb[84];
    __shared__ float sgw[672];
    __shared__ float sh[64 * 85];
    __shared__ float sC[6800];
    __shared__ float shb2[80];
    __shared__ float shb[10];
    __shared__ float slog[64 * 9];
    __shared__ float swt[128];
    __shared__ int   sei[128];
    const int tid = threadIdx.x;
    const int n0 = blockIdx.x * 64;

    {
        const float4* g = (const float4*)(h1 + (size_t)n0 * 120);
        float4* s = (float4*)sh1;
        for (int i = tid; i < 1920; i += 256) s[i] = g[i];
    }
    for (int i = tid; i < 2520; i += 256) {
        int o = i / 30, k4 = (i % 30) * 4;
        float4 v = *(const float4*)(f2w + (size_t)o * 120 + k4);
        float* d = sfw + o * 121 + k4;
        d[0] = v.x; d[1] = v.y; d[2] = v.z; d[3] = v.w;
    }
    for (int i = tid; i < 6720; i += 256) sC[(i / 84) * 85 + (i % 84)] = Cw[i];
    for (int i = tid; i < 672; i += 256) sgw[i] = gw[i];
    if (tid < 84) sfb[tid] = f2b[tid];
    if (tid < 80) shb2[tid] = hb2[tid];
    if (tid < 10) shb[tid] = headb[tid];
    __syncthreads();

    for (int i = tid; i < 5376; i += 256) {
        const int t = i / 84, o = i % 84;
        const float* a = sh1 + t * 120;
        const float* wr = sfw + o * 121;
        float s = 0.f;
        #pragma unroll 8
        for (int k = 0; k < 120; ++k) s = fmaf(a[k], wr[k], s);
        sh[t * 85 + o] = fmaxf(s + sfb[o], 0.f);
    }
    __syncthreads();

    for (int i = tid; i < 512; i += 256) {
        const int t = i / 8, e = i % 8;
        const float* a = sh + t * 85;
        float s = 0.f;
        #pragma unroll 4
        for (int d = 0; d < 84; ++d) s = fmaf(a[d], sgw[d * 8 + e], s);
        slog[t * 9 + e] = s;
    }
    __syncthreads();

    if (tid < 64) {
        const float* l = slog + tid * 9;
        float m1 = l[0]; int i1 = 0;
        #pragma unroll
        for (int e = 1; e < 8; ++e) if (l[e] > m1) { m1 = l[e]; i1 = e; }
        float m2 = -1e30f; int i2 = 0;
        #pragma unroll
        for (int e = 0; e < 8; ++e) if (e != i1 && l[e] > m2) { m2 = l[e]; i2 = e; }
        const float r = expf(m2 - m1);
        const float inv = 1.f / (1.f + r);
        swt[tid * 2] = inv; swt[tid * 2 + 1] = r * inv;
        sei[tid * 2] = i1; sei[tid * 2 + 1] = i2;
    }
    __syncthreads();

    for (int i = tid; i < 640; i += 256) {
        const int t = i / 10, o = i % 10;
        const float* a = sh + t * 85;
        const float w0 = swt[t * 2], w1 = swt[t * 2 + 1];
        const int e0 = sei[t * 2], e1 = sei[t * 2 + 1];
        const float* c0 = sC + (e0 * 10 + o) * 85;
        const float* c1 = sC + (e1 * 10 + o) * 85;
        float s0 = 0.f, s1 = 0.f;
        #pragma unroll 4
        for (int d = 0; d < 84; ++d) {
            s0 = fmaf(a[d], c0[d], s0);
            s1 = fmaf(a[d], c1[d], s1);
        }
        out[(size_t)(n0 + t) * 10 + o] =
            shb[o] + w0 * (s0 + shb2[e0 * 10 + o]) + w1 * (s1 + shb2[e1 * 10 + o]);
    }
}

extern "C" void kernel_launch(void* const* d_in, const int* in_sizes, int n_in,
                              void* d_out, int out_size, void* d_ws, size_t ws_size,
                              hipStream_t stream) {
    const float* x   = (const float*)d_in[0];
    const float* c1w = (const float*)d_in[1];
    const float* c1b = (const float*)d_in[2];
    const float* c2w = (const float*)d_in[3];
    const float* c2b = (const float*)d_in[4];
    const float* f1w = (const float*)d_in[5];
    const float* f1b = (const float*)d_in[6];
    const float* f2w = (const float*)d_in[7];
    const float* f2b = (const float*)d_in[8];
    const float* gw  = (const float*)d_in[9];
    const float* ew  = (const float*)d_in[10];
    const float* eb  = (const float*)d_in[11];
    const float* hw  = (const float*)d_in[12];
    const float* hb  = (const float*)d_in[13];
    float* out = (float*)d_out;

    const int N = in_sizes[0] / 3072;   // 16384

    float* ws = (float*)d_ws;
    float* p2  = ws;                           // N*400
    float* h1  = p2 + (size_t)N * 400;         // N*120
    float* C   = h1 + (size_t)N * 120;         // 6720
    float* hb2 = C + 6720;                     // 80

    k_conv12<<<N, 256, 0, stream>>>(x, c1w, c1b, c2w, c2b, p2);
    k_fc1<<<N / 64, 256, 0, stream>>>(p2, f1w, f1b, h1);
    k_compose<<<8, 256, 0, stream>>>(ew, eb, hw, C, hb2);
    k_tail<<<N / 64, 256, 0, stream>>>(h1, f2w, f2b, gw, C, hb2, hb, out);
}

// Round 13
// 332.939 us; speedup vs baseline: 1.3284x; 1.3284x over previous
//
#include <hip/hip_runtime.h>
#include <math.h>

typedef _Float16 half8 __attribute__((ext_vector_type(8)));
typedef float f32x4 __attribute__((ext_vector_type(4)));

__device__ inline uint splitpack(float v) {
    _Float16 h = (_Float16)v;
    float r = v - (float)h;
    _Float16 l = (_Float16)r;
    return (uint)__builtin_bit_cast(unsigned short, h) |
           ((uint)__builtin_bit_cast(unsigned short, l) << 16);
}
__device__ inline _Float16 lo16h(uint u) { return __builtin_bit_cast(_Float16, (unsigned short)(u & 0xffffu)); }
__device__ inline _Float16 hi16h(uint u) { return __builtin_bit_cast(_Float16, (unsigned short)(u >> 16)); }
__device__ inline uint packhh(_Float16 a, _Float16 b) {
    return (uint)__builtin_bit_cast(unsigned short, a) |
           ((uint)__builtin_bit_cast(unsigned short, b) << 16);
}
__device__ inline float dpp_max8(float v) {
    int x = __builtin_amdgcn_mov_dpp(__builtin_bit_cast(int, v), 0x128, 0xf, 0xf, true);
    return fmaxf(v, __builtin_bit_cast(float, x));
}

// ---------------- conv1 (round-10 verbatim): x -> p1 packed ----------------
__global__ __launch_bounds__(256) void k_conv1(const float* __restrict__ x,
                                               const float* __restrict__ w,
                                               const float* __restrict__ b,
                                               uint* __restrict__ p1) {
    __shared__ uint simg[6720];
    const int tid  = threadIdx.x;
    const int lane = tid & 63;
    const int wv   = tid >> 6;
    const int n0   = blockIdx.x * 2;

    const int colb = lane & 15;
    const int c  = colb & 7, dx = colb >> 3;
    const int g  = lane >> 4;
    const int qr = g;

    half8 bh[3], bl[3];
    #pragma unroll
    for (int ks = 0; ks < 3; ++ks)
        #pragma unroll
        for (int jj = 0; jj < 8; ++jj) {
            int pi = jj >> 1, e = jj & 1;
            int rho = g * 4 + pi;
            float val = 0.f;
            if (rho < 15 && c < 6) {
                int ci = rho / 5, ky = rho % 5;
                int kx = ks * 2 + e - dx;
                if (kx >= 0 && kx < 5) val = w[c * 75 + ci * 25 + ky * 5 + kx];
            }
            _Float16 hh = (_Float16)val;
            bh[ks][jj] = hh;
            bl[ks][jj] = (_Float16)(val - (float)hh);
        }
    const float bias = (c < 6) ? b[c] : 0.f;

    for (int i = tid; i < 1536; i += 256) {
        int im = i / 768;
        int rem = i - im * 768;
        int plane = rem >> 8, rr = (rem & 255) >> 3, f = rem & 7;
        float4 v = *(const float4*)(x + ((size_t)(n0 + im) * 3 + plane) * 1024 + rr * 32 + f * 4);
        _Float16 h0 = (_Float16)v.x, h1 = (_Float16)v.y, h2 = (_Float16)v.z, h3 = (_Float16)v.w;
        _Float16 l0 = (_Float16)(v.x - (float)h0), l1 = (_Float16)(v.y - (float)h1);
        _Float16 l2 = (_Float16)(v.z - (float)h2), l3 = (_Float16)(v.w - (float)h3);
        int base = im * 3360 + plane * 1120 + rr * 35 + f * 2;
        simg[base]      = packhh(h0, h1);
        simg[base + 1]  = packhh(h2, h3);
        simg[base + 16] = packhh(l0, l1);
        simg[base + 17] = packhh(l2, l3);
    }
    __syncthreads();

    int poff[4];
    #pragma unroll
    for (int pi = 0; pi < 4; ++pi) {
        int rho = g * 4 + pi;
        if (rho > 14) rho = 14;
        poff[pi] = (rho / 5) * 1120 + (rho % 5) * 35;
    }

    for (int t0 = wv; t0 < 50; t0 += 8) {
        const int t1 = (t0 + 4 < 50) ? (t0 + 4) : t0;
        const int im0 = (t0 >= 25) ? 1 : 0, tl0 = t0 - im0 * 25;
        const int im1 = (t1 >= 25) ? 1 : 0, tl1 = t1 - im1 * 25;
        int r0c = tl0 * 16 + colb; if (r0c > 391) r0c = 391;
        int r1c = tl1 * 16 + colb; if (r1c > 391) r1c = 391;
        int qx0 = (r0c * 586) >> 14, yy0 = r0c - qx0 * 28;
        int qx1 = (r1c * 586) >> 14, yy1 = r1c - qx1 * 28;
        const uint* base0 = simg + im0 * 3360 + yy0 * 35 + qx0;
        const uint* base1 = simg + im1 * 3360 + yy1 * 35 + qx1;

        f32x4 A0[2] = {{0.f,0.f,0.f,0.f},{0.f,0.f,0.f,0.f}};
        f32x4 A1[2] = {{0.f,0.f,0.f,0.f},{0.f,0.f,0.f,0.f}};
        int c0 = 0, c1 = 0;
        #pragma unroll
        for (int ks = 0; ks < 3; ++ks) {
            uint h0[4], l0[4], h1[4], l1[4];
            #pragma unroll
            for (int pi = 0; pi < 4; ++pi) {
                const uint* a0p = base0 + poff[pi];
                const uint* a1p = base1 + poff[pi];
                h0[pi] = a0p[ks];  l0[pi] = a0p[16 + ks];
                h1[pi] = a1p[ks];  l1[pi] = a1p[16 + ks];
            }
            uint4 hv0; hv0.x = h0[0]; hv0.y = h0[1]; hv0.z = h0[2]; hv0.w = h0[3];
            uint4 lv0; lv0.x = l0[0]; lv0.y = l0[1]; lv0.z = l0[2]; lv0.w = l0[3];
            uint4 hv1; hv1.x = h1[0]; hv1.y = h1[1]; hv1.z = h1[2]; hv1.w = h1[3];
            uint4 lv1; lv1.x = l1[0]; lv1.y = l1[1]; lv1.z = l1[2]; lv1.w = l1[3];
            half8 ah0 = __builtin_bit_cast(half8, hv0);
            half8 al0 = __builtin_bit_cast(half8, lv0);
            half8 ah1 = __builtin_bit_cast(half8, hv1);
            half8 al1 = __builtin_bit_cast(half8, lv1);
            A0[c0 & 1] = __builtin_amdgcn_mfma_f32_16x16x32_f16(ah0, bh[ks], A0[c0 & 1], 0, 0, 0); ++c0;
            A1[c1 & 1] = __builtin_amdgcn_mfma_f32_16x16x32_f16(ah1, bh[ks], A1[c1 & 1], 0, 0, 0); ++c1;
            A0[c0 & 1] = __builtin_amdgcn_mfma_f32_16x16x32_f16(ah0, bl[ks], A0[c0 & 1], 0, 0, 0); ++c0;
            A1[c1 & 1] = __builtin_amdgcn_mfma_f32_16x16x32_f16(ah1, bl[ks], A1[c1 & 1], 0, 0, 0); ++c1;
            A0[c0 & 1] = __builtin_amdgcn_mfma_f32_16x16x32_f16(al0, bh[ks], A0[c0 & 1], 0, 0, 0); ++c0;
            A1[c1 & 1] = __builtin_amdgcn_mfma_f32_16x16x32_f16(al1, bh[ks], A1[c1 & 1], 0, 0, 0); ++c1;
        }
        {
            f32x4 acc;
            #pragma unroll
            for (int i = 0; i < 4; ++i) acc[i] = A0[0][i] + A0[1][i];
            float p01 = dpp_max8(fmaxf(acc[0], acc[1]));
            float p23 = dpp_max8(fmaxf(acc[2], acc[3]));
            if (dx == 0 && c < 6) {
                uint* outb = p1 + ((size_t)(n0 + im0) * 6 + c) * 196;
                int r0 = tl0 * 16 + qr * 4;
                if (r0 + 1 < 392) {
                    int qxa = (r0 * 586) >> 14, ya = r0 - qxa * 28;
                    outb[(ya >> 1) * 14 + qxa] = splitpack(fmaxf(p01 + bias, 0.f));
                }
                int r2 = r0 + 2;
                if (r2 + 1 < 392) {
                    int qxb = (r2 * 586) >> 14, yb = r2 - qxb * 28;
                    outb[(yb >> 1) * 14 + qxb] = splitpack(fmaxf(p23 + bias, 0.f));
                }
            }
        }
        if (t1 != t0) {
            f32x4 acc;
            #pragma unroll
            for (int i = 0; i < 4; ++i) acc[i] = A1[0][i] + A1[1][i];
            float p01 = dpp_max8(fmaxf(acc[0], acc[1]));
            float p23 = dpp_max8(fmaxf(acc[2], acc[3]));
            if (dx == 0 && c < 6) {
                uint* outb = p1 + ((size_t)(n0 + im1) * 6 + c) * 196;
                int r0 = tl1 * 16 + qr * 4;
                if (r0 + 1 < 392) {
                    int qxa = (r0 * 586) >> 14, ya = r0 - qxa * 28;
                    outb[(ya >> 1) * 14 + qxa] = splitpack(fmaxf(p01 + bias, 0.f));
                }
                int r2 = r0 + 2;
                if (r2 + 1 < 392) {
                    int qxb = (r2 * 586) >> 14, yb = r2 - qxb * 28;
                    outb[(yb >> 1) * 14 + qxb] = splitpack(fmaxf(p23 + bias, 0.f));
                }
            }
        }
    }
}

// ---------------- conv2 (round-10 verbatim): p1 packed -> p2 fp32 ----------------
__global__ __launch_bounds__(256) void k_conv2(const uint* __restrict__ p1,
                                               const float* __restrict__ w,
                                               const float* __restrict__ b,
                                               float* __restrict__ p2) {
    __shared__ uint simg[4 * 1260];
    __shared__ uint sB[5 * 64 * 8];
    __shared__ float sb[16];
    const int tid  = threadIdx.x;
    const int lane = tid & 63;
    const int wv   = tid >> 6;
    const int n0   = blockIdx.x * 4;

    for (int i = tid; i < 4704; i += 256) {
        int img = i / 1176, rem = i % 1176;
        int c = rem / 196, rr = rem % 196;
        int y = rr / 14, xx = rr % 14;
        simg[img * 1260 + c * 210 + y * 15 + xx] = p1[(size_t)(n0 + img) * 1176 + rem];
    }
    for (int p = tid; p < 320; p += 256) {
        int ks = p >> 6, l = p & 63;
        int nn = l & 15, g = l >> 4;
        #pragma unroll
        for (int j = 0; j < 8; ++j) {
            int k = ks * 32 + g * 8 + j;
            float wv_ = (k < 150) ? w[nn * 150 + k] : 0.f;
            sB[p * 8 + j] = splitpack(wv_);
        }
    }
    if (tid < 16) sb[tid] = b[tid];
    __syncthreads();

    const int qw = (lane & 15) >> 2;
    const int dy = (lane >> 1) & 1, dx = lane & 1;
    const int g  = lane >> 4;
    int offs[40];
    #pragma unroll
    for (int ks = 0; ks < 5; ++ks)
        #pragma unroll
        for (int j = 0; j < 8; ++j) {
            int k = ks * 32 + g * 8 + j;
            int o = 0;
            if (k < 150) { int ci = k / 25, r = k % 25; o = ci * 210 + (r / 5) * 15 + (r % 5); }
            offs[ks * 8 + j] = o;
        }
    half8 bh[5], bl[5];
    #pragma unroll
    for (int ks = 0; ks < 5; ++ks)
        #pragma unroll
        for (int j = 0; j < 8; ++j) {
            uint u = sB[(ks * 64 + lane) * 8 + j];
            bh[ks][j] = lo16h(u); bl[ks][j] = hi16h(u);
        }

    const uint* img = simg + wv * 1260;
    const int n  = n0 + wv;
    const int cc = lane & 15;
    const int qr = lane >> 4;
    const float bias = sb[cc];
    float* outb = p2 + (size_t)n * 400 + cc * 25;

    for (int t = 0; t < 7; ++t) {
        int qa = t * 4 + qw; if (qa > 24) qa = 24;
        int qy = qa / 5, qx = qa % 5;
        int base = (2 * qy + dy) * 15 + (2 * qx + dx);
        f32x4 acc2[2] = {{0.f,0.f,0.f,0.f},{0.f,0.f,0.f,0.f}};
        int pp = 0;
        #pragma unroll
        for (int ks = 0; ks < 5; ++ks) {
            uint up[8];
            #pragma unroll
            for (int j = 0; j < 8; ++j) up[j] = img[base + offs[ks * 8 + j]];
            half8 ah, al;
            #pragma unroll
            for (int j = 0; j < 8; ++j) { ah[j] = lo16h(up[j]); al[j] = hi16h(up[j]); }
            acc2[pp & 1] = __builtin_amdgcn_mfma_f32_16x16x32_f16(ah, bh[ks], acc2[pp & 1], 0, 0, 0); ++pp;
            acc2[pp & 1] = __builtin_amdgcn_mfma_f32_16x16x32_f16(ah, bl[ks], acc2[pp & 1], 0, 0, 0); ++pp;
            acc2[pp & 1] = __builtin_amdgcn_mfma_f32_16x16x32_f16(al, bh[ks], acc2[pp & 1], 0, 0, 0); ++pp;
        }
        int qc = t * 4 + qr;
        if (qc < 25) {
            float m = fmaxf(fmaxf(acc2[0][0] + acc2[1][0], acc2[0][1] + acc2[1][1]),
                            fmaxf(acc2[0][2] + acc2[1][2], acc2[0][3] + acc2[1][3]));
            outb[qc] = fmaxf(m + bias, 0.f);
        }
    }
}

// ---------------- fc1: 512 threads (8 waves) for latency hiding ----------------
__global__ __launch_bounds__(512) void k_fc1(const float* __restrict__ p2,
                                             const float* __restrict__ w,
                                             const float* __restrict__ b,
                                             float* __restrict__ h1) {
    __shared__ float sa[64 * 100];
    __shared__ float swt[120 * 101];
    const int tid = threadIdx.x;
    const int n0 = blockIdx.x * 64;
    const int tc = tid % 30, tr = tid / 30;
    float acc[8][4];
    #pragma unroll
    for (int i = 0; i < 8; ++i)
        #pragma unroll
        for (int j = 0; j < 4; ++j) acc[i][j] = 0.f;

    for (int kt = 0; kt < 4; ++kt) {
        __syncthreads();
        for (int i = tid; i < 1600; i += 512) {
            int r = i / 25, k4 = (i % 25) * 4;
            float4 v = *(const float4*)(p2 + (size_t)(n0 + r) * 400 + kt * 100 + k4);
            *(float4*)(sa + r * 100 + k4) = v;
        }
        for (int i = tid; i < 3000; i += 512) {
            int c = i / 25, k4 = (i % 25) * 4;
            float4 v = *(const float4*)(w + (size_t)c * 400 + kt * 100 + k4);
            float* d = swt + c * 101 + k4;
            d[0] = v.x; d[1] = v.y; d[2] = v.z; d[3] = v.w;
        }
        __syncthreads();
        if (tr < 8) {
            #pragma unroll 4
            for (int k = 0; k < 100; ++k) {
                float av[8], wv[4];
                #pragma unroll
                for (int i = 0; i < 8; ++i) av[i] = sa[(tr * 8 + i) * 100 + k];
                #pragma unroll
                for (int j = 0; j < 4; ++j) wv[j] = swt[(tc * 4 + j) * 101 + k];
                #pragma unroll
                for (int i = 0; i < 8; ++i)
                    #pragma unroll
                    for (int j = 0; j < 4; ++j) acc[i][j] = fmaf(av[i], wv[j], acc[i][j]);
            }
        }
    }
    if (tr < 8) {
        #pragma unroll
        for (int j = 0; j < 4; ++j) {
            const int o = tc * 4 + j;
            const float bo = b[o];
            #pragma unroll
            for (int i = 0; i < 8; ++i) {
                const int rr = n0 + tr * 8 + i;
                h1[(size_t)rr * 120 + o] = fmaxf(acc[i][j] + bo, 0.f);
            }
        }
    }
}

// ---------------- compose: C[e][o][d] = sum_j head_w[o][j]*expert_w[e][j][d] ----------------
__global__ __launch_bounds__(256) void k_compose(const float* __restrict__ ew,
                                                 const float* __restrict__ eb,
                                                 const float* __restrict__ hw,
                                                 float* __restrict__ C,
                                                 float* __restrict__ hb2) {
    __shared__ float shw[840];
    __shared__ float seb[672];
    const int e = blockIdx.x, tid = threadIdx.x;
    for (int i = tid; i < 840; i += 256) shw[i] = hw[i];
    for (int i = tid; i < 672; i += 256) seb[i] = eb[i];
    __syncthreads();
    for (int i = tid; i < 840; i += 256) {
        int o = i / 84, d = i % 84;
        float s = 0.f;
        for (int j = 0; j < 84; ++j)
            s = fmaf(shw[o * 84 + j], ew[((size_t)e * 84 + j) * 84 + d], s);
        C[e * 840 + i] = s;
    }
    if (tid < 10) {
        float s = 0.f;
        for (int j = 0; j < 84; ++j) s = fmaf(shw[tid * 84 + j], seb[e * 84 + j], s);
        hb2[e * 10 + tid] = s;
    }
}

// ---------------- tail: 512 threads (8 waves) ----------------
__global__ __launch_bounds__(512) void k_tail(const float* __restrict__ h1,
                                              const float* __restrict__ f2w,
                                              const float* __restrict__ f2b,
                                              const float* __restrict__ gw,
                                              const float* __restrict__ Cw,
                                              const float* __restrict__ hb2,
                                              const float* __restrict__ headb,
                                              float* __restrict__ out) {
    __shared__ float sh1[64 * 120];
    __shared__ float sfw[84 * 121];
    __shared__ float sfb[84];
    __shared__ float sgw[672];
    __shared__ float sh[64 * 85];
    __shared__ float sC[6800];
    __shared__ float shb2[80];
    __shared__ float shb[10];
    __shared__ float slog[64 * 9];
    __shared__ float swt[128];
    __shared__ int   sei[128];
    const int tid = threadIdx.x;
    const int n0 = blockIdx.x * 64;

    {
        const float4* g = (const float4*)(h1 + (size_t)n0 * 120);
        float4* s = (float4*)sh1;
        for (int i = tid; i < 1920; i += 512) s[i] = g[i];
    }
    for (int i = tid; i < 2520; i += 512) {
        int o = i / 30, k4 = (i % 30) * 4;
        float4 v = *(const float4*)(f2w + (size_t)o * 120 + k4);
        float* d = sfw + o * 121 + k4;
        d[0] = v.x; d[1] = v.y; d[2] = v.z; d[3] = v.w;
    }
    for (int i = tid; i < 6720; i += 512) sC[(i / 84) * 85 + (i % 84)] = Cw[i];
    for (int i = tid; i < 672; i += 512) sgw[i] = gw[i];
    if (tid < 84) sfb[tid] = f2b[tid];
    if (tid < 80) shb2[tid] = hb2[tid];
    if (tid < 10) shb[tid] = headb[tid];
    __syncthreads();

    for (int i = tid; i < 5376; i += 512) {
        const int t = i / 84, o = i % 84;
        const float* a = sh1 + t * 120;
        const float* wr = sfw + o * 121;
        float s = 0.f;
        #pragma unroll 8
        for (int k = 0; k < 120; ++k) s = fmaf(a[k], wr[k], s);
        sh[t * 85 + o] = fmaxf(s + sfb[o], 0.f);
    }
    __syncthreads();

    if (tid < 512) {
        const int t = tid / 8, e = tid % 8;
        const float* a = sh + t * 85;
        float s = 0.f;
        #pragma unroll 4
        for (int d = 0; d < 84; ++d) s = fmaf(a[d], sgw[d * 8 + e], s);
        slog[t * 9 + e] = s;
    }
    __syncthreads();

    if (tid < 64) {
        const float* l = slog + tid * 9;
        float m1 = l[0]; int i1 = 0;
        #pragma unroll
        for (int e = 1; e < 8; ++e) if (l[e] > m1) { m1 = l[e]; i1 = e; }
        float m2 = -1e30f; int i2 = 0;
        #pragma unroll
        for (int e = 0; e < 8; ++e) if (e != i1 && l[e] > m2) { m2 = l[e]; i2 = e; }
        const float r = expf(m2 - m1);
        const float inv = 1.f / (1.f + r);
        swt[tid * 2] = inv; swt[tid * 2 + 1] = r * inv;
        sei[tid * 2] = i1; sei[tid * 2 + 1] = i2;
    }
    __syncthreads();

    for (int i = tid; i < 640; i += 512) {
        const int t = i / 10, o = i % 10;
        const float* a = sh + t * 85;
        const float w0 = swt[t * 2], w1 = swt[t * 2 + 1];
        const int e0 = sei[t * 2], e1 = sei[t * 2 + 1];
        const float* c0 = sC + (e0 * 10 + o) * 85;
        const float* c1 = sC + (e1 * 10 + o) * 85;
        float s0 = 0.f, s1 = 0.f;
        #pragma unroll 4
        for (int d = 0; d < 84; ++d) {
            s0 = fmaf(a[d], c0[d], s0);
            s1 = fmaf(a[d], c1[d], s1);
        }
        out[(size_t)(n0 + t) * 10 + o] =
            shb[o] + w0 * (s0 + shb2[e0 * 10 + o]) + w1 * (s1 + shb2[e1 * 10 + o]);
    }
}

extern "C" void kernel_launch(void* const* d_in, const int* in_sizes, int n_in,
                              void* d_out, int out_size, void* d_ws, size_t ws_size,
                              hipStream_t stream) {
    const float* x   = (const float*)d_in[0];
    const float* c1w = (const float*)d_in[1];
    const float* c1b = (const float*)d_in[2];
    const float* c2w = (const float*)d_in[3];
    const float* c2b = (const float*)d_in[4];
    const float* f1w = (const float*)d_in[5];
    const float* f1b = (const float*)d_in[6];
    const float* f2w = (const float*)d_in[7];
    const float* f2b = (const float*)d_in[8];
    const float* gw  = (const float*)d_in[9];
    const float* ew  = (const float*)d_in[10];
    const float* eb  = (const float*)d_in[11];
    const float* hw  = (const float*)d_in[12];
    const float* hb  = (const float*)d_in[13];
    float* out = (float*)d_out;

    const int N = in_sizes[0] / 3072;   // 16384

    float* ws = (float*)d_ws;
    uint*  p1  = (uint*)ws;                    // N*1176 uints (packed hi/lo)
    float* p2  = ws + (size_t)N * 1176;        // N*400
    float* h1  = p2 + (size_t)N * 400;         // N*120
    float* C   = h1 + (size_t)N * 120;         // 6720
    float* hb2 = C + 6720;                     // 80

    k_conv1<<<N / 2, 256, 0, stream>>>(x, c1w, c1b, p1);
    k_conv2<<<N / 4, 256, 0, stream>>>(p1, c2w, c2b, p2);
    k_fc1<<<N / 64, 512, 0, stream>>>(p2, f1w, f1b, h1);
    k_compose<<<8, 256, 0, stream>>>(ew, eb, hw, C, hb2);
    k_tail<<<N / 64, 512, 0, stream>>>(h1, f2w, f2b, gw, C, hb2, hb, out);
}

// Round 15
// 301.094 us; speedup vs baseline: 1.4689x; 1.1058x over previous
//
#include <hip/hip_runtime.h>
#include <math.h>

typedef _Float16 half8 __attribute__((ext_vector_type(8)));
typedef float f32x4 __attribute__((ext_vector_type(4)));

__device__ inline uint splitpack(float v) {
    _Float16 h = (_Float16)v;
    float r = v - (float)h;
    _Float16 l = (_Float16)r;
    return (uint)__builtin_bit_cast(unsigned short, h) |
           ((uint)__builtin_bit_cast(unsigned short, l) << 16);
}
__device__ inline _Float16 lo16h(uint u) { return __builtin_bit_cast(_Float16, (unsigned short)(u & 0xffffu)); }
__device__ inline _Float16 hi16h(uint u) { return __builtin_bit_cast(_Float16, (unsigned short)(u >> 16)); }
__device__ inline uint packhh(_Float16 a, _Float16 b) {
    return (uint)__builtin_bit_cast(unsigned short, a) |
           ((uint)__builtin_bit_cast(unsigned short, b) << 16);
}
__device__ inline float dpp_max8(float v) {
    int x = __builtin_amdgcn_mov_dpp(__builtin_bit_cast(int, v), 0x128, 0xf, 0xf, true);
    return fmaxf(v, __builtin_bit_cast(float, x));
}

// ---------------- conv1 (round-10 verbatim): x -> p1 packed ----------------
__global__ __launch_bounds__(256) void k_conv1(const float* __restrict__ x,
                                               const float* __restrict__ w,
                                               const float* __restrict__ b,
                                               uint* __restrict__ p1) {
    __shared__ uint simg[6720];
    const int tid  = threadIdx.x;
    const int lane = tid & 63;
    const int wv   = tid >> 6;
    const int n0   = blockIdx.x * 2;

    const int colb = lane & 15;
    const int c  = colb & 7, dx = colb >> 3;
    const int g  = lane >> 4;
    const int qr = g;

    half8 bh[3], bl[3];
    #pragma unroll
    for (int ks = 0; ks < 3; ++ks)
        #pragma unroll
        for (int jj = 0; jj < 8; ++jj) {
            int pi = jj >> 1, e = jj & 1;
            int rho = g * 4 + pi;
            float val = 0.f;
            if (rho < 15 && c < 6) {
                int ci = rho / 5, ky = rho % 5;
                int kx = ks * 2 + e - dx;
                if (kx >= 0 && kx < 5) val = w[c * 75 + ci * 25 + ky * 5 + kx];
            }
            _Float16 hh = (_Float16)val;
            bh[ks][jj] = hh;
            bl[ks][jj] = (_Float16)(val - (float)hh);
        }
    const float bias = (c < 6) ? b[c] : 0.f;

    for (int i = tid; i < 1536; i += 256) {
        int im = i / 768;
        int rem = i - im * 768;
        int plane = rem >> 8, rr = (rem & 255) >> 3, f = rem & 7;
        float4 v = *(const float4*)(x + ((size_t)(n0 + im) * 3 + plane) * 1024 + rr * 32 + f * 4);
        _Float16 h0 = (_Float16)v.x, h1 = (_Float16)v.y, h2 = (_Float16)v.z, h3 = (_Float16)v.w;
        _Float16 l0 = (_Float16)(v.x - (float)h0), l1 = (_Float16)(v.y - (float)h1);
        _Float16 l2 = (_Float16)(v.z - (float)h2), l3 = (_Float16)(v.w - (float)h3);
        int base = im * 3360 + plane * 1120 + rr * 35 + f * 2;
        simg[base]      = packhh(h0, h1);
        simg[base + 1]  = packhh(h2, h3);
        simg[base + 16] = packhh(l0, l1);
        simg[base + 17] = packhh(l2, l3);
    }
    __syncthreads();

    int poff[4];
    #pragma unroll
    for (int pi = 0; pi < 4; ++pi) {
        int rho = g * 4 + pi;
        if (rho > 14) rho = 14;
        poff[pi] = (rho / 5) * 1120 + (rho % 5) * 35;
    }

    for (int t0 = wv; t0 < 50; t0 += 8) {
        const int t1 = (t0 + 4 < 50) ? (t0 + 4) : t0;
        const int im0 = (t0 >= 25) ? 1 : 0, tl0 = t0 - im0 * 25;
        const int im1 = (t1 >= 25) ? 1 : 0, tl1 = t1 - im1 * 25;
        int r0c = tl0 * 16 + colb; if (r0c > 391) r0c = 391;
        int r1c = tl1 * 16 + colb; if (r1c > 391) r1c = 391;
        int qx0 = (r0c * 586) >> 14, yy0 = r0c - qx0 * 28;
        int qx1 = (r1c * 586) >> 14, yy1 = r1c - qx1 * 28;
        const uint* base0 = simg + im0 * 3360 + yy0 * 35 + qx0;
        const uint* base1 = simg + im1 * 3360 + yy1 * 35 + qx1;

        f32x4 A0[2] = {{0.f,0.f,0.f,0.f},{0.f,0.f,0.f,0.f}};
        f32x4 A1[2] = {{0.f,0.f,0.f,0.f},{0.f,0.f,0.f,0.f}};
        int c0 = 0, c1 = 0;
        #pragma unroll
        for (int ks = 0; ks < 3; ++ks) {
            uint h0[4], l0[4], h1[4], l1[4];
            #pragma unroll
            for (int pi = 0; pi < 4; ++pi) {
                const uint* a0p = base0 + poff[pi];
                const uint* a1p = base1 + poff[pi];
                h0[pi] = a0p[ks];  l0[pi] = a0p[16 + ks];
                h1[pi] = a1p[ks];  l1[pi] = a1p[16 + ks];
            }
            uint4 hv0; hv0.x = h0[0]; hv0.y = h0[1]; hv0.z = h0[2]; hv0.w = h0[3];
            uint4 lv0; lv0.x = l0[0]; lv0.y = l0[1]; lv0.z = l0[2]; lv0.w = l0[3];
            uint4 hv1; hv1.x = h1[0]; hv1.y = h1[1]; hv1.z = h1[2]; hv1.w = h1[3];
            uint4 lv1; lv1.x = l1[0]; lv1.y = l1[1]; lv1.z = l1[2]; lv1.w = l1[3];
            half8 ah0 = __builtin_bit_cast(half8, hv0);
            half8 al0 = __builtin_bit_cast(half8, lv0);
            half8 ah1 = __builtin_bit_cast(half8, hv1);
            half8 al1 = __builtin_bit_cast(half8, lv1);
            A0[c0 & 1] = __builtin_amdgcn_mfma_f32_16x16x32_f16(ah0, bh[ks], A0[c0 & 1], 0, 0, 0); ++c0;
            A1[c1 & 1] = __builtin_amdgcn_mfma_f32_16x16x32_f16(ah1, bh[ks], A1[c1 & 1], 0, 0, 0); ++c1;
            A0[c0 & 1] = __builtin_amdgcn_mfma_f32_16x16x32_f16(ah0, bl[ks], A0[c0 & 1], 0, 0, 0); ++c0;
            A1[c1 & 1] = __builtin_amdgcn_mfma_f32_16x16x32_f16(ah1, bl[ks], A1[c1 & 1], 0, 0, 0); ++c1;
            A0[c0 & 1] = __builtin_amdgcn_mfma_f32_16x16x32_f16(al0, bh[ks], A0[c0 & 1], 0, 0, 0); ++c0;
            A1[c1 & 1] = __builtin_amdgcn_mfma_f32_16x16x32_f16(al1, bh[ks], A1[c1 & 1], 0, 0, 0); ++c1;
        }
        {
            f32x4 acc;
            #pragma unroll
            for (int i = 0; i < 4; ++i) acc[i] = A0[0][i] + A0[1][i];
            float p01 = dpp_max8(fmaxf(acc[0], acc[1]));
            float p23 = dpp_max8(fmaxf(acc[2], acc[3]));
            if (dx == 0 && c < 6) {
                uint* outb = p1 + ((size_t)(n0 + im0) * 6 + c) * 196;
                int r0 = tl0 * 16 + qr * 4;
                if (r0 + 1 < 392) {
                    int qxa = (r0 * 586) >> 14, ya = r0 - qxa * 28;
                    outb[(ya >> 1) * 14 + qxa] = splitpack(fmaxf(p01 + bias, 0.f));
                }
                int r2 = r0 + 2;
                if (r2 + 1 < 392) {
                    int qxb = (r2 * 586) >> 14, yb = r2 - qxb * 28;
                    outb[(yb >> 1) * 14 + qxb] = splitpack(fmaxf(p23 + bias, 0.f));
                }
            }
        }
        if (t1 != t0) {
            f32x4 acc;
            #pragma unroll
            for (int i = 0; i < 4; ++i) acc[i] = A1[0][i] + A1[1][i];
            float p01 = dpp_max8(fmaxf(acc[0], acc[1]));
            float p23 = dpp_max8(fmaxf(acc[2], acc[3]));
            if (dx == 0 && c < 6) {
                uint* outb = p1 + ((size_t)(n0 + im1) * 6 + c) * 196;
                int r0 = tl1 * 16 + qr * 4;
                if (r0 + 1 < 392) {
                    int qxa = (r0 * 586) >> 14, ya = r0 - qxa * 28;
                    outb[(ya >> 1) * 14 + qxa] = splitpack(fmaxf(p01 + bias, 0.f));
                }
                int r2 = r0 + 2;
                if (r2 + 1 < 392) {
                    int qxb = (r2 * 586) >> 14, yb = r2 - qxb * 28;
                    outb[(yb >> 1) * 14 + qxb] = splitpack(fmaxf(p23 + bias, 0.f));
                }
            }
        }
    }
}

// ---------------- conv2: K=192 permutation, read2-merged gathers, B in registers ----------------
// Pad column 14 of each stride-15 row is READ by the kx=5 pad slots (B=0) — it MUST be
// written (0) to keep outputs deterministic: leftover LDS garbage can decode as fp16 Inf/NaN
// and 0*Inf = NaN would poison the MFMA accumulator (round-14 tripwire failure).
__global__ __launch_bounds__(256) void k_conv2(const uint* __restrict__ p1,
                                               const float* __restrict__ w,
                                               const float* __restrict__ b,
                                               float* __restrict__ p2) {
    __shared__ uint simg[4 * 1260];
    const int tid  = threadIdx.x;
    const int lane = tid & 63;
    const int wv   = tid >> 6;
    const int n0   = blockIdx.x * 4;
    const int g  = lane >> 4;
    const int cc = lane & 15;
    const int qr = g;

    // stage full region incl. zeroed pad column 14
    for (int i = tid; i < 5040; i += 256) {
        int img = i / 1260, rem = i % 1260;
        int c = rem / 210, rr = rem % 210;
        int y = rr / 15, xx = rr % 15;
        uint v = 0u;
        if (xx < 14) v = p1[(size_t)(n0 + img) * 1176 + c * 196 + y * 14 + xx];
        simg[i] = v;
    }

    // B fragments in registers
    half8 bh[6], bl[6];
    #pragma unroll
    for (int ks = 0; ks < 6; ++ks)
        #pragma unroll
        for (int jj = 0; jj < 8; ++jj) {
            int pi = jj >> 1, e = jj & 1;
            int rho = (ks / 3) * 16 + g * 4 + pi;
            int kx = (ks % 3) * 2 + e;
            float val = 0.f;
            if (rho < 30 && kx < 5) {
                int ci = rho / 5, ky = rho % 5;
                val = w[cc * 150 + ci * 25 + ky * 5 + kx];
            }
            _Float16 hh = (_Float16)val;
            bh[ks][jj] = hh;
            bl[ks][jj] = (_Float16)(val - (float)hh);
        }
    const float bias = b[cc];
    __syncthreads();

    int poff2[8];                          // row base per (sel,pi)
    #pragma unroll
    for (int sp = 0; sp < 8; ++sp) {
        int sel = sp >> 2, pi = sp & 3;
        int rho = sel * 16 + g * 4 + pi;
        if (rho > 29) rho = 29;            // pad rows: safe in-bounds read, B=0
        poff2[sp] = (rho / 5) * 210 + (rho % 5) * 15;
    }

    const uint* img = simg + wv * 1260;
    const int qw  = (lane & 15) >> 2;
    const int dy  = (lane >> 1) & 1, dxx = lane & 1;
    float* outb = p2 + (size_t)(n0 + wv) * 400 + cc * 25;

    for (int t = 0; t < 7; ++t) {
        int qa = t * 4 + qw; if (qa > 24) qa = 24;
        int qy = qa / 5, qx = qa % 5;
        int base = (2 * qy + dy) * 15 + (2 * qx + dxx);
        f32x4 acc2[2] = {{0.f,0.f,0.f,0.f},{0.f,0.f,0.f,0.f}};
        int pp = 0;
        #pragma unroll
        for (int sel = 0; sel < 2; ++sel) {
            uint P[4][6];
            #pragma unroll
            for (int pi = 0; pi < 4; ++pi) {
                const uint* ap = img + base + poff2[sel * 4 + pi];
                #pragma unroll
                for (int k = 0; k < 6; ++k) P[pi][k] = ap[k];  // 3x ds_read2_b32
            }
            #pragma unroll
            for (int ksr = 0; ksr < 3; ++ksr) {
                const int ks = sel * 3 + ksr;
                uint hu[4], lu[4];
                #pragma unroll
                for (int pi = 0; pi < 4; ++pi) {
                    uint d0 = P[pi][ksr * 2], d1 = P[pi][ksr * 2 + 1];
                    hu[pi] = __builtin_amdgcn_perm(d1, d0, 0x05040100u);
                    lu[pi] = __builtin_amdgcn_perm(d1, d0, 0x07060302u);
                }
                uint4 hv; hv.x = hu[0]; hv.y = hu[1]; hv.z = hu[2]; hv.w = hu[3];
                uint4 lv; lv.x = lu[0]; lv.y = lu[1]; lv.z = lu[2]; lv.w = lu[3];
                half8 ah = __builtin_bit_cast(half8, hv);
                half8 al = __builtin_bit_cast(half8, lv);
                acc2[pp & 1] = __builtin_amdgcn_mfma_f32_16x16x32_f16(ah, bh[ks], acc2[pp & 1], 0, 0, 0); ++pp;
                acc2[pp & 1] = __builtin_amdgcn_mfma_f32_16x16x32_f16(ah, bl[ks], acc2[pp & 1], 0, 0, 0); ++pp;
                acc2[pp & 1] = __builtin_amdgcn_mfma_f32_16x16x32_f16(al, bh[ks], acc2[pp & 1], 0, 0, 0); ++pp;
            }
        }
        int qc = t * 4 + qr;
        if (qc < 25) {
            float m = fmaxf(fmaxf(acc2[0][0] + acc2[1][0], acc2[0][1] + acc2[1][1]),
                            fmaxf(acc2[0][2] + acc2[1][2], acc2[0][3] + acc2[1][3]));
            outb[qc] = fmaxf(m + bias, 0.f);
        }
    }
}

// ---------------- fc1: 512 threads (8 waves) for latency hiding ----------------
__global__ __launch_bounds__(512) void k_fc1(const float* __restrict__ p2,
                                             const float* __restrict__ w,
                                             const float* __restrict__ b,
                                             float* __restrict__ h1) {
    __shared__ float sa[64 * 100];
    __shared__ float swt[120 * 101];
    const int tid = threadIdx.x;
    const int n0 = blockIdx.x * 64;
    const int tc = tid % 30, tr = tid / 30;
    float acc[8][4];
    #pragma unroll
    for (int i = 0; i < 8; ++i)
        #pragma unroll
        for (int j = 0; j < 4; ++j) acc[i][j] = 0.f;

    for (int kt = 0; kt < 4; ++kt) {
        __syncthreads();
        for (int i = tid; i < 1600; i += 512) {
            int r = i / 25, k4 = (i % 25) * 4;
            float4 v = *(const float4*)(p2 + (size_t)(n0 + r) * 400 + kt * 100 + k4);
            *(float4*)(sa + r * 100 + k4) = v;
        }
        for (int i = tid; i < 3000; i += 512) {
            int c = i / 25, k4 = (i % 25) * 4;
            float4 v = *(const float4*)(w + (size_t)c * 400 + kt * 100 + k4);
            float* d = swt + c * 101 + k4;
            d[0] = v.x; d[1] = v.y; d[2] = v.z; d[3] = v.w;
        }
        __syncthreads();
        if (tr < 8) {
            #pragma unroll 4
            for (int k = 0; k < 100; ++k) {
                float av[8], wv[4];
                #pragma unroll
                for (int i = 0; i < 8; ++i) av[i] = sa[(tr * 8 + i) * 100 + k];
                #pragma unroll
                for (int j = 0; j < 4; ++j) wv[j] = swt[(tc * 4 + j) * 101 + k];
                #pragma unroll
                for (int i = 0; i < 8; ++i)
                    #pragma unroll
                    for (int j = 0; j < 4; ++j) acc[i][j] = fmaf(av[i], wv[j], acc[i][j]);
            }
        }
    }
    if (tr < 8) {
        #pragma unroll
        for (int j = 0; j < 4; ++j) {
            const int o = tc * 4 + j;
            const float bo = b[o];
            #pragma unroll
            for (int i = 0; i < 8; ++i) {
                const int rr = n0 + tr * 8 + i;
                h1[(size_t)rr * 120 + o] = fmaxf(acc[i][j] + bo, 0.f);
            }
        }
    }
}

// ---------------- compose: C[e][o][d] = sum_j head_w[o][j]*expert_w[e][j][d] ----------------
__global__ __launch_bounds__(256) void k_compose(const float* __restrict__ ew,
                                                 const float* __restrict__ eb,
                                                 const float* __restrict__ hw,
                                                 float* __restrict__ C,
                                                 float* __restrict__ hb2) {
    __shared__ float shw[840];
    __shared__ float seb[672];
    const int e = blockIdx.x, tid = threadIdx.x;
    for (int i = tid; i < 840; i += 256) shw[i] = hw[i];
    for (int i = tid; i < 672; i += 256) seb[i] = eb[i];
    __syncthreads();
    for (int i = tid; i < 840; i += 256) {
        int o = i / 84, d = i % 84;
        float s = 0.f;
        for (int j = 0; j < 84; ++j)
            s = fmaf(shw[o * 84 + j], ew[((size_t)e * 84 + j) * 84 + d], s);
        C[e * 840 + i] = s;
    }
    if (tid < 10) {
        float s = 0.f;
        for (int j = 0; j < 84; ++j) s = fmaf(shw[tid * 84 + j], seb[e * 84 + j], s);
        hb2[e * 10 + tid] = s;
    }
}

// ---------------- tail: 512 threads (8 waves) ----------------
__global__ __launch_bounds__(512) void k_tail(const float* __restrict__ h1,
                                              const float* __restrict__ f2w,
                                              const float* __restrict__ f2b,
                                              const float* __restrict__ gw,
                                              const float* __restrict__ Cw,
                                              const float* __restrict__ hb2,
                                              const float* __restrict__ headb,
                                              float* __restrict__ out) {
    __shared__ float sh1[64 * 120];
    __shared__ float sfw[84 * 121];
    __shared__ float sfb[84];
    __shared__ float sgw[672];
    __shared__ float sh[64 * 85];
    __shared__ float sC[6800];
    __shared__ float shb2[80];
    __shared__ float shb[10];
    __shared__ float slog[64 * 9];
    __shared__ float swt[128];
    __shared__ int   sei[128];
    const int tid = threadIdx.x;
    const int n0 = blockIdx.x * 64;

    {
        const float4* g = (const float4*)(h1 + (size_t)n0 * 120);
        float4* s = (float4*)sh1;
        for (int i = tid; i < 1920; i += 512) s[i] = g[i];
    }
    for (int i = tid; i < 2520; i += 512) {
        int o = i / 30, k4 = (i % 30) * 4;
        float4 v = *(const float4*)(f2w + (size_t)o * 120 + k4);
        float* d = sfw + o * 121 + k4;
        d[0] = v.x; d[1] = v.y; d[2] = v.z; d[3] = v.w;
    }
    for (int i = tid; i < 6720; i += 512) sC[(i / 84) * 85 + (i % 84)] = Cw[i];
    for (int i = tid; i < 672; i += 512) sgw[i] = gw[i];
    if (tid < 84) sfb[tid] = f2b[tid];
    if (tid < 80) shb2[tid] = hb2[tid];
    if (tid < 10) shb[tid] = headb[tid];
    __syncthreads();

    for (int i = tid; i < 5376; i += 512) {
        const int t = i / 84, o = i % 84;
        const float* a = sh1 + t * 120;
        const float* wr = sfw + o * 121;
        float s = 0.f;
        #pragma unroll 8
        for (int k = 0; k < 120; ++k) s = fmaf(a[k], wr[k], s);
        sh[t * 85 + o] = fmaxf(s + sfb[o], 0.f);
    }
    __syncthreads();

    {
        const int t = tid / 8, e = tid % 8;
        const float* a = sh + t * 85;
        float s = 0.f;
        #pragma unroll 4
        for (int d = 0; d < 84; ++d) s = fmaf(a[d], sgw[d * 8 + e], s);
        slog[t * 9 + e] = s;
    }
    __syncthreads();

    if (tid < 64) {
        const float* l = slog + tid * 9;
        float m1 = l[0]; int i1 = 0;
        #pragma unroll
        for (int e = 1; e < 8; ++e) if (l[e] > m1) { m1 = l[e]; i1 = e; }
        float m2 = -1e30f; int i2 = 0;
        #pragma unroll
        for (int e = 0; e < 8; ++e) if (e != i1 && l[e] > m2) { m2 = l[e]; i2 = e; }
        const float r = expf(m2 - m1);
        const float inv = 1.f / (1.f + r);
        swt[tid * 2] = inv; swt[tid * 2 + 1] = r * inv;
        sei[tid * 2] = i1; sei[tid * 2 + 1] = i2;
    }
    __syncthreads();

    for (int i = tid; i < 640; i += 512) {
        const int t = i / 10, o = i % 10;
        const float* a = sh + t * 85;
        const float w0 = swt[t * 2], w1 = swt[t * 2 + 1];
        const int e0 = sei[t * 2], e1 = sei[t * 2 + 1];
        const float* c0 = sC + (e0 * 10 + o) * 85;
        const float* c1 = sC + (e1 * 10 + o) * 85;
        float s0 = 0.f, s1 = 0.f;
        #pragma unroll 4
        for (int d = 0; d < 84; ++d) {
            s0 = fmaf(a[d], c0[d], s0);
            s1 = fmaf(a[d], c1[d], s1);
        }
        out[(size_t)(n0 + t) * 10 + o] =
            shb[o] + w0 * (s0 + shb2[e0 * 10 + o]) + w1 * (s1 + shb2[e1 * 10 + o]);
    }
}

extern "C" void kernel_launch(void* const* d_in, const int* in_sizes, int n_in,
                              void* d_out, int out_size, void* d_ws, size_t ws_size,
                              hipStream_t stream) {
    const float* x   = (const float*)d_in[0];
    const float* c1w = (const float*)d_in[1];
    const float* c1b = (const float*)d_in[2];
    const float* c2w = (const float*)d_in[3];
    const float* c2b = (const float*)d_in[4];
    const float* f1w = (const float*)d_in[5];
    const float* f1b = (const float*)d_in[6];
    const float* f2w = (const float*)d_in[7];
    const float* f2b = (const float*)d_in[8];
    const float* gw  = (const float*)d_in[9];
    const float* ew  = (const float*)d_in[10];
    const float* eb  = (const float*)d_in[11];
    const float* hw  = (const float*)d_in[12];
    const float* hb  = (const float*)d_in[13];
    float* out = (float*)d_out;

    const int N = in_sizes[0] / 3072;   // 16384

    float* ws = (float*)d_ws;
    uint*  p1  = (uint*)ws;                    // N*1176 uints (packed hi/lo)
    float* p2  = ws + (size_t)N * 1176;        // N*400
    float* h1  = p2 + (size_t)N * 400;         // N*120
    float* C   = h1 + (size_t)N * 120;         // 6720
    float* hb2 = C + 6720;                     // 80

    k_conv1<<<N / 2, 256, 0, stream>>>(x, c1w, c1b, p1);
    k_conv2<<<N / 4, 256, 0, stream>>>(p1, c2w, c2b, p2);
    k_fc1<<<N / 64, 512, 0, stream>>>(p2, f1w, f1b, h1);
    k_compose<<<8, 256, 0, stream>>>(ew, eb, hw, C, hb2);
    k_tail<<<N / 64, 512, 0, stream>>>(h1, f2w, f2b, gw, C, hb2, hb, out);
}

// Round 16
// 298.545 us; speedup vs baseline: 1.4814x; 1.0085x over previous
//
#include <hip/hip_runtime.h>
#include <math.h>

typedef _Float16 half8 __attribute__((ext_vector_type(8)));
typedef float f32x4 __attribute__((ext_vector_type(4)));

__device__ inline uint splitpack(float v) {
    _Float16 h = (_Float16)v;
    float r = v - (float)h;
    _Float16 l = (_Float16)r;
    return (uint)__builtin_bit_cast(unsigned short, h) |
           ((uint)__builtin_bit_cast(unsigned short, l) << 16);
}
__device__ inline _Float16 lo16h(uint u) { return __builtin_bit_cast(_Float16, (unsigned short)(u & 0xffffu)); }
__device__ inline _Float16 hi16h(uint u) { return __builtin_bit_cast(_Float16, (unsigned short)(u >> 16)); }
__device__ inline uint packhh(_Float16 a, _Float16 b) {
    return (uint)__builtin_bit_cast(unsigned short, a) |
           ((uint)__builtin_bit_cast(unsigned short, b) << 16);
}
__device__ inline float dpp_max8(float v) {
    int x = __builtin_amdgcn_mov_dpp(__builtin_bit_cast(int, v), 0x128, 0xf, 0xf, true);
    return fmaxf(v, __builtin_bit_cast(float, x));
}

// ---------------- conv1 (round-15 verbatim): x -> p1 packed ----------------
__global__ __launch_bounds__(256) void k_conv1(const float* __restrict__ x,
                                               const float* __restrict__ w,
                                               const float* __restrict__ b,
                                               uint* __restrict__ p1) {
    __shared__ uint simg[6720];
    const int tid  = threadIdx.x;
    const int lane = tid & 63;
    const int wv   = tid >> 6;
    const int n0   = blockIdx.x * 2;

    const int colb = lane & 15;
    const int c  = colb & 7, dx = colb >> 3;
    const int g  = lane >> 4;
    const int qr = g;

    half8 bh[3], bl[3];
    #pragma unroll
    for (int ks = 0; ks < 3; ++ks)
        #pragma unroll
        for (int jj = 0; jj < 8; ++jj) {
            int pi = jj >> 1, e = jj & 1;
            int rho = g * 4 + pi;
            float val = 0.f;
            if (rho < 15 && c < 6) {
                int ci = rho / 5, ky = rho % 5;
                int kx = ks * 2 + e - dx;
                if (kx >= 0 && kx < 5) val = w[c * 75 + ci * 25 + ky * 5 + kx];
            }
            _Float16 hh = (_Float16)val;
            bh[ks][jj] = hh;
            bl[ks][jj] = (_Float16)(val - (float)hh);
        }
    const float bias = (c < 6) ? b[c] : 0.f;

    for (int i = tid; i < 1536; i += 256) {
        int im = i / 768;
        int rem = i - im * 768;
        int plane = rem >> 8, rr = (rem & 255) >> 3, f = rem & 7;
        float4 v = *(const float4*)(x + ((size_t)(n0 + im) * 3 + plane) * 1024 + rr * 32 + f * 4);
        _Float16 h0 = (_Float16)v.x, h1 = (_Float16)v.y, h2 = (_Float16)v.z, h3 = (_Float16)v.w;
        _Float16 l0 = (_Float16)(v.x - (float)h0), l1 = (_Float16)(v.y - (float)h1);
        _Float16 l2 = (_Float16)(v.z - (float)h2), l3 = (_Float16)(v.w - (float)h3);
        int base = im * 3360 + plane * 1120 + rr * 35 + f * 2;
        simg[base]      = packhh(h0, h1);
        simg[base + 1]  = packhh(h2, h3);
        simg[base + 16] = packhh(l0, l1);
        simg[base + 17] = packhh(l2, l3);
    }
    __syncthreads();

    int poff[4];
    #pragma unroll
    for (int pi = 0; pi < 4; ++pi) {
        int rho = g * 4 + pi;
        if (rho > 14) rho = 14;
        poff[pi] = (rho / 5) * 1120 + (rho % 5) * 35;
    }

    for (int t0 = wv; t0 < 50; t0 += 8) {
        const int t1 = (t0 + 4 < 50) ? (t0 + 4) : t0;
        const int im0 = (t0 >= 25) ? 1 : 0, tl0 = t0 - im0 * 25;
        const int im1 = (t1 >= 25) ? 1 : 0, tl1 = t1 - im1 * 25;
        int r0c = tl0 * 16 + colb; if (r0c > 391) r0c = 391;
        int r1c = tl1 * 16 + colb; if (r1c > 391) r1c = 391;
        int qx0 = (r0c * 586) >> 14, yy0 = r0c - qx0 * 28;
        int qx1 = (r1c * 586) >> 14, yy1 = r1c - qx1 * 28;
        const uint* base0 = simg + im0 * 3360 + yy0 * 35 + qx0;
        const uint* base1 = simg + im1 * 3360 + yy1 * 35 + qx1;

        f32x4 A0[2] = {{0.f,0.f,0.f,0.f},{0.f,0.f,0.f,0.f}};
        f32x4 A1[2] = {{0.f,0.f,0.f,0.f},{0.f,0.f,0.f,0.f}};
        int c0 = 0, c1 = 0;
        #pragma unroll
        for (int ks = 0; ks < 3; ++ks) {
            uint h0[4], l0[4], h1[4], l1[4];
            #pragma unroll
            for (int pi = 0; pi < 4; ++pi) {
                const uint* a0p = base0 + poff[pi];
                const uint* a1p = base1 + poff[pi];
                h0[pi] = a0p[ks];  l0[pi] = a0p[16 + ks];
                h1[pi] = a1p[ks];  l1[pi] = a1p[16 + ks];
            }
            uint4 hv0; hv0.x = h0[0]; hv0.y = h0[1]; hv0.z = h0[2]; hv0.w = h0[3];
            uint4 lv0; lv0.x = l0[0]; lv0.y = l0[1]; lv0.z = l0[2]; lv0.w = l0[3];
            uint4 hv1; hv1.x = h1[0]; hv1.y = h1[1]; hv1.z = h1[2]; hv1.w = h1[3];
            uint4 lv1; lv1.x = l1[0]; lv1.y = l1[1]; lv1.z = l1[2]; lv1.w = l1[3];
            half8 ah0 = __builtin_bit_cast(half8, hv0);
            half8 al0 = __builtin_bit_cast(half8, lv0);
            half8 ah1 = __builtin_bit_cast(half8, hv1);
            half8 al1 = __builtin_bit_cast(half8, lv1);
            A0[c0 & 1] = __builtin_amdgcn_mfma_f32_16x16x32_f16(ah0, bh[ks], A0[c0 & 1], 0, 0, 0); ++c0;
            A1[c1 & 1] = __builtin_amdgcn_mfma_f32_16x16x32_f16(ah1, bh[ks], A1[c1 & 1], 0, 0, 0); ++c1;
            A0[c0 & 1] = __builtin_amdgcn_mfma_f32_16x16x32_f16(ah0, bl[ks], A0[c0 & 1], 0, 0, 0); ++c0;
            A1[c1 & 1] = __builtin_amdgcn_mfma_f32_16x16x32_f16(ah1, bl[ks], A1[c1 & 1], 0, 0, 0); ++c1;
            A0[c0 & 1] = __builtin_amdgcn_mfma_f32_16x16x32_f16(al0, bh[ks], A0[c0 & 1], 0, 0, 0); ++c0;
            A1[c1 & 1] = __builtin_amdgcn_mfma_f32_16x16x32_f16(al1, bh[ks], A1[c1 & 1], 0, 0, 0); ++c1;
        }
        {
            f32x4 acc;
            #pragma unroll
            for (int i = 0; i < 4; ++i) acc[i] = A0[0][i] + A0[1][i];
            float p01 = dpp_max8(fmaxf(acc[0], acc[1]));
            float p23 = dpp_max8(fmaxf(acc[2], acc[3]));
            if (dx == 0 && c < 6) {
                uint* outb = p1 + ((size_t)(n0 + im0) * 6 + c) * 196;
                int r0 = tl0 * 16 + qr * 4;
                if (r0 + 1 < 392) {
                    int qxa = (r0 * 586) >> 14, ya = r0 - qxa * 28;
                    outb[(ya >> 1) * 14 + qxa] = splitpack(fmaxf(p01 + bias, 0.f));
                }
                int r2 = r0 + 2;
                if (r2 + 1 < 392) {
                    int qxb = (r2 * 586) >> 14, yb = r2 - qxb * 28;
                    outb[(yb >> 1) * 14 + qxb] = splitpack(fmaxf(p23 + bias, 0.f));
                }
            }
        }
        if (t1 != t0) {
            f32x4 acc;
            #pragma unroll
            for (int i = 0; i < 4; ++i) acc[i] = A1[0][i] + A1[1][i];
            float p01 = dpp_max8(fmaxf(acc[0], acc[1]));
            float p23 = dpp_max8(fmaxf(acc[2], acc[3]));
            if (dx == 0 && c < 6) {
                uint* outb = p1 + ((size_t)(n0 + im1) * 6 + c) * 196;
                int r0 = tl1 * 16 + qr * 4;
                if (r0 + 1 < 392) {
                    int qxa = (r0 * 586) >> 14, ya = r0 - qxa * 28;
                    outb[(ya >> 1) * 14 + qxa] = splitpack(fmaxf(p01 + bias, 0.f));
                }
                int r2 = r0 + 2;
                if (r2 + 1 < 392) {
                    int qxb = (r2 * 586) >> 14, yb = r2 - qxb * 28;
                    outb[(yb >> 1) * 14 + qxb] = splitpack(fmaxf(p23 + bias, 0.f));
                }
            }
        }
    }
}

// ---------------- conv2 (round-15 verbatim): p1 packed -> p2 fp32 ----------------
__global__ __launch_bounds__(256) void k_conv2(const uint* __restrict__ p1,
                                               const float* __restrict__ w,
                                               const float* __restrict__ b,
                                               float* __restrict__ p2) {
    __shared__ uint simg[4 * 1260];
    const int tid  = threadIdx.x;
    const int lane = tid & 63;
    const int wv   = tid >> 6;
    const int n0   = blockIdx.x * 4;
    const int g  = lane >> 4;
    const int cc = lane & 15;
    const int qr = g;

    for (int i = tid; i < 5040; i += 256) {
        int img = i / 1260, rem = i % 1260;
        int c = rem / 210, rr = rem % 210;
        int y = rr / 15, xx = rr % 15;
        uint v = 0u;
        if (xx < 14) v = p1[(size_t)(n0 + img) * 1176 + c * 196 + y * 14 + xx];
        simg[i] = v;
    }

    half8 bh[6], bl[6];
    #pragma unroll
    for (int ks = 0; ks < 6; ++ks)
        #pragma unroll
        for (int jj = 0; jj < 8; ++jj) {
            int pi = jj >> 1, e = jj & 1;
            int rho = (ks / 3) * 16 + g * 4 + pi;
            int kx = (ks % 3) * 2 + e;
            float val = 0.f;
            if (rho < 30 && kx < 5) {
                int ci = rho / 5, ky = rho % 5;
                val = w[cc * 150 + ci * 25 + ky * 5 + kx];
            }
            _Float16 hh = (_Float16)val;
            bh[ks][jj] = hh;
            bl[ks][jj] = (_Float16)(val - (float)hh);
        }
    const float bias = b[cc];
    __syncthreads();

    int poff2[8];
    #pragma unroll
    for (int sp = 0; sp < 8; ++sp) {
        int sel = sp >> 2, pi = sp & 3;
        int rho = sel * 16 + g * 4 + pi;
        if (rho > 29) rho = 29;
        poff2[sp] = (rho / 5) * 210 + (rho % 5) * 15;
    }

    const uint* img = simg + wv * 1260;
    const int qw  = (lane & 15) >> 2;
    const int dy  = (lane >> 1) & 1, dxx = lane & 1;
    float* outb = p2 + (size_t)(n0 + wv) * 400 + cc * 25;

    for (int t = 0; t < 7; ++t) {
        int qa = t * 4 + qw; if (qa > 24) qa = 24;
        int qy = qa / 5, qx = qa % 5;
        int base = (2 * qy + dy) * 15 + (2 * qx + dxx);
        f32x4 acc2[2] = {{0.f,0.f,0.f,0.f},{0.f,0.f,0.f,0.f}};
        int pp = 0;
        #pragma unroll
        for (int sel = 0; sel < 2; ++sel) {
            uint P[4][6];
            #pragma unroll
            for (int pi = 0; pi < 4; ++pi) {
                const uint* ap = img + base + poff2[sel * 4 + pi];
                #pragma unroll
                for (int k = 0; k < 6; ++k) P[pi][k] = ap[k];
            }
            #pragma unroll
            for (int ksr = 0; ksr < 3; ++ksr) {
                const int ks = sel * 3 + ksr;
                uint hu[4], lu[4];
                #pragma unroll
                for (int pi = 0; pi < 4; ++pi) {
                    uint d0 = P[pi][ksr * 2], d1 = P[pi][ksr * 2 + 1];
                    hu[pi] = __builtin_amdgcn_perm(d1, d0, 0x05040100u);
                    lu[pi] = __builtin_amdgcn_perm(d1, d0, 0x07060302u);
                }
                uint4 hv; hv.x = hu[0]; hv.y = hu[1]; hv.z = hu[2]; hv.w = hu[3];
                uint4 lv; lv.x = lu[0]; lv.y = lu[1]; lv.z = lu[2]; lv.w = lu[3];
                half8 ah = __builtin_bit_cast(half8, hv);
                half8 al = __builtin_bit_cast(half8, lv);
                acc2[pp & 1] = __builtin_amdgcn_mfma_f32_16x16x32_f16(ah, bh[ks], acc2[pp & 1], 0, 0, 0); ++pp;
                acc2[pp & 1] = __builtin_amdgcn_mfma_f32_16x16x32_f16(ah, bl[ks], acc2[pp & 1], 0, 0, 0); ++pp;
                acc2[pp & 1] = __builtin_amdgcn_mfma_f32_16x16x32_f16(al, bh[ks], acc2[pp & 1], 0, 0, 0); ++pp;
            }
        }
        int qc = t * 4 + qr;
        if (qc < 25) {
            float m = fmaxf(fmaxf(acc2[0][0] + acc2[1][0], acc2[0][1] + acc2[1][1]),
                            fmaxf(acc2[0][2] + acc2[1][2], acc2[0][3] + acc2[1][3]));
            outb[qc] = fmaxf(m + bias, 0.f);
        }
    }
}

// ---------------- compose: C[e][o][d] = sum_j head_w[o][j]*expert_w[e][j][d] ----------------
__global__ __launch_bounds__(256) void k_compose(const float* __restrict__ ew,
                                                 const float* __restrict__ eb,
                                                 const float* __restrict__ hw,
                                                 float* __restrict__ C,
                                                 float* __restrict__ hb2) {
    __shared__ float shw[840];
    __shared__ float seb[672];
    const int e = blockIdx.x, tid = threadIdx.x;
    for (int i = tid; i < 840; i += 256) shw[i] = hw[i];
    for (int i = tid; i < 672; i += 256) seb[i] = eb[i];
    __syncthreads();
    for (int i = tid; i < 840; i += 256) {
        int o = i / 84, d = i % 84;
        float s = 0.f;
        for (int j = 0; j < 84; ++j)
            s = fmaf(shw[o * 84 + j], ew[((size_t)e * 84 + j) * 84 + d], s);
        C[e * 840 + i] = s;
    }
    if (tid < 10) {
        float s = 0.f;
        for (int j = 0; j < 84; ++j) s = fmaf(shw[tid * 84 + j], seb[e * 84 + j], s);
        hb2[e * 10 + tid] = s;
    }
}

// ---------------- fused fc1+fc2+gate+MoE+head: p2 -> out, h1 stays in LDS ----------------
// Phase1 (fc1) uses region as {sa[6400], swt[12120]}.  Phase2 (tail) reuses region:
// sfw[0,10164) sC[10164,16964) sh[16964,22404) sgw[22404,23076) shb2[23076,23156)
// shb[23156,23168) slog[23168,23744) swt2[23744,23872).  sh1 (h1) is persistent.
__global__ __launch_bounds__(512) void k_fc1tail(const float* __restrict__ p2,
                                                 const float* __restrict__ f1w,
                                                 const float* __restrict__ f1b,
                                                 const float* __restrict__ f2w,
                                                 const float* __restrict__ f2b,
                                                 const float* __restrict__ gw,
                                                 const float* __restrict__ Cw,
                                                 const float* __restrict__ hb2,
                                                 const float* __restrict__ headb,
                                                 float* __restrict__ out) {
    __shared__ float region[23872];
    __shared__ float sh1[7680];          // h1: [64][120]
    __shared__ int   sei[128];
    const int tid = threadIdx.x;
    const int n0 = blockIdx.x * 64;

    // ---------- phase 1: fc1 ----------
    {
        float* sa  = region;             // [64][100]
        float* swt = region + 6400;      // [120][101]
        const int tc = tid % 30, tr = tid / 30;
        float acc[8][4];
        #pragma unroll
        for (int i = 0; i < 8; ++i)
            #pragma unroll
            for (int j = 0; j < 4; ++j) acc[i][j] = 0.f;

        for (int kt = 0; kt < 4; ++kt) {
            __syncthreads();
            for (int i = tid; i < 1600; i += 512) {
                int r = i / 25, k4 = (i % 25) * 4;
                float4 v = *(const float4*)(p2 + (size_t)(n0 + r) * 400 + kt * 100 + k4);
                *(float4*)(sa + r * 100 + k4) = v;
            }
            for (int i = tid; i < 3000; i += 512) {
                int c = i / 25, k4 = (i % 25) * 4;
                float4 v = *(const float4*)(f1w + (size_t)c * 400 + kt * 100 + k4);
                float* d = swt + c * 101 + k4;
                d[0] = v.x; d[1] = v.y; d[2] = v.z; d[3] = v.w;
            }
            __syncthreads();
            if (tr < 8) {
                #pragma unroll 4
                for (int k = 0; k < 100; ++k) {
                    float av[8], wv[4];
                    #pragma unroll
                    for (int i = 0; i < 8; ++i) av[i] = sa[(tr * 8 + i) * 100 + k];
                    #pragma unroll
                    for (int j = 0; j < 4; ++j) wv[j] = swt[(tc * 4 + j) * 101 + k];
                    #pragma unroll
                    for (int i = 0; i < 8; ++i)
                        #pragma unroll
                        for (int j = 0; j < 4; ++j) acc[i][j] = fmaf(av[i], wv[j], acc[i][j]);
                }
            }
        }
        __syncthreads();                 // protect region before phase-2 overwrite
        if (tr < 8) {
            #pragma unroll
            for (int j = 0; j < 4; ++j) {
                const int o = tc * 4 + j;
                const float bo = f1b[o];
                #pragma unroll
                for (int i = 0; i < 8; ++i)
                    sh1[(tr * 8 + i) * 120 + o] = fmaxf(acc[i][j] + bo, 0.f);
            }
        }
    }

    // ---------- phase 2: fc2 + gate + top2 + MoE + head ----------
    float* sfw  = region;
    float* sC   = region + 10164;
    float* sh   = region + 16964;
    float* sgw  = region + 22404;
    float* shb2s= region + 23076;
    float* shb  = region + 23156;
    float* slog = region + 23168;
    float* swt2 = region + 23744;

    for (int i = tid; i < 2520; i += 512) {
        int o = i / 30, k4 = (i % 30) * 4;
        float4 v = *(const float4*)(f2w + (size_t)o * 120 + k4);
        float* d = sfw + o * 121 + k4;
        d[0] = v.x; d[1] = v.y; d[2] = v.z; d[3] = v.w;
    }
    for (int i = tid; i < 6720; i += 512) sC[(i / 84) * 85 + (i % 84)] = Cw[i];
    for (int i = tid; i < 672; i += 512) sgw[i] = gw[i];
    if (tid < 84) shb[100] = shb[100];   // no-op placeholder to keep structure clear
    if (tid < 80) shb2s[tid] = hb2[tid];
    if (tid < 10) shb[tid] = headb[tid];
    __shared__ float sfb[84];
    if (tid < 84) sfb[tid] = f2b[tid];
    __syncthreads();

    for (int i = tid; i < 5376; i += 512) {
        const int t = i / 84, o = i % 84;
        const float* a = sh1 + t * 120;
        const float* wr = sfw + o * 121;
        float s = 0.f;
        #pragma unroll 8
        for (int k = 0; k < 120; ++k) s = fmaf(a[k], wr[k], s);
        sh[t * 85 + o] = fmaxf(s + sfb[o], 0.f);
    }
    __syncthreads();

    {
        const int t = tid / 8, e = tid % 8;
        const float* a = sh + t * 85;
        float s = 0.f;
        #pragma unroll 4
        for (int d = 0; d < 84; ++d) s = fmaf(a[d], sgw[d * 8 + e], s);
        slog[t * 9 + e] = s;
    }
    __syncthreads();

    if (tid < 64) {
        const float* l = slog + tid * 9;
        float m1 = l[0]; int i1 = 0;
        #pragma unroll
        for (int e = 1; e < 8; ++e) if (l[e] > m1) { m1 = l[e]; i1 = e; }
        float m2 = -1e30f; int i2 = 0;
        #pragma unroll
        for (int e = 0; e < 8; ++e) if (e != i1 && l[e] > m2) { m2 = l[e]; i2 = e; }
        const float r = expf(m2 - m1);
        const float inv = 1.f / (1.f + r);
        swt2[tid * 2] = inv; swt2[tid * 2 + 1] = r * inv;
        sei[tid * 2] = i1; sei[tid * 2 + 1] = i2;
    }
    __syncthreads();

    for (int i = tid; i < 640; i += 512) {
        const int t = i / 10, o = i % 10;
        const float* a = sh + t * 85;
        const float w0 = swt2[t * 2], w1 = swt2[t * 2 + 1];
        const int e0 = sei[t * 2], e1 = sei[t * 2 + 1];
        const float* c0 = sC + (e0 * 10 + o) * 85;
        const float* c1 = sC + (e1 * 10 + o) * 85;
        float s0 = 0.f, s1 = 0.f;
        #pragma unroll 4
        for (int d = 0; d < 84; ++d) {
            s0 = fmaf(a[d], c0[d], s0);
            s1 = fmaf(a[d], c1[d], s1);
        }
        out[(size_t)(n0 + t) * 10 + o] =
            shb[o] + w0 * (s0 + shb2s[e0 * 10 + o]) + w1 * (s1 + shb2s[e1 * 10 + o]);
    }
}

extern "C" void kernel_launch(void* const* d_in, const int* in_sizes, int n_in,
                              void* d_out, int out_size, void* d_ws, size_t ws_size,
                              hipStream_t stream) {
    const float* x   = (const float*)d_in[0];
    const float* c1w = (const float*)d_in[1];
    const float* c1b = (const float*)d_in[2];
    const float* c2w = (const float*)d_in[3];
    const float* c2b = (const float*)d_in[4];
    const float* f1w = (const float*)d_in[5];
    const float* f1b = (const float*)d_in[6];
    const float* f2w = (const float*)d_in[7];
    const float* f2b = (const float*)d_in[8];
    const float* gw  = (const float*)d_in[9];
    const float* ew  = (const float*)d_in[10];
    const float* eb  = (const float*)d_in[11];
    const float* hw  = (const float*)d_in[12];
    const float* hb  = (const float*)d_in[13];
    float* out = (float*)d_out;

    const int N = in_sizes[0] / 3072;   // 16384

    float* ws = (float*)d_ws;
    uint*  p1  = (uint*)ws;                    // N*1176 uints (packed hi/lo)
    float* p2  = ws + (size_t)N * 1176;        // N*400
    float* C   = p2 + (size_t)N * 400;         // 6720
    float* hb2 = C + 6720;                     // 80

    k_conv1<<<N / 2, 256, 0, stream>>>(x, c1w, c1b, p1);
    k_conv2<<<N / 4, 256, 0, stream>>>(p1, c2w, c2b, p2);
    k_compose<<<8, 256, 0, stream>>>(ew, eb, hw, C, hb2);
    k_fc1tail<<<N / 64, 512, 0, stream>>>(p2, f1w, f1b, f2w, f2b, gw, C, hb2, hb, out);
}

// Round 17
// 293.987 us; speedup vs baseline: 1.5044x; 1.0155x over previous
//
#include <hip/hip_runtime.h>
#include <math.h>

typedef _Float16 half8 __attribute__((ext_vector_type(8)));
typedef float f32x4 __attribute__((ext_vector_type(4)));

__device__ inline uint splitpack(float v) {
    _Float16 h = (_Float16)v;
    float r = v - (float)h;
    _Float16 l = (_Float16)r;
    return (uint)__builtin_bit_cast(unsigned short, h) |
           ((uint)__builtin_bit_cast(unsigned short, l) << 16);
}
__device__ inline _Float16 lo16h(uint u) { return __builtin_bit_cast(_Float16, (unsigned short)(u & 0xffffu)); }
__device__ inline _Float16 hi16h(uint u) { return __builtin_bit_cast(_Float16, (unsigned short)(u >> 16)); }
__device__ inline uint packhh(_Float16 a, _Float16 b) {
    return (uint)__builtin_bit_cast(unsigned short, a) |
           ((uint)__builtin_bit_cast(unsigned short, b) << 16);
}
__device__ inline float dpp_max8(float v) {
    int x = __builtin_amdgcn_mov_dpp(__builtin_bit_cast(int, v), 0x128, 0xf, 0xf, true);
    return fmaxf(v, __builtin_bit_cast(float, x));
}

// ---------------- conv1: x -> p1 packed, emitted in conv2's padded layout [N][1260] ----------------
// p1[n][c*210 + y*15 + qx], pad column 14 zeroed explicitly (determinism invariant: conv2's
// kx=5 pad slots read col 14 with B=0; garbage fp16 Inf would poison 0*Inf=NaN).
__global__ __launch_bounds__(256) void k_conv1(const float* __restrict__ x,
                                               const float* __restrict__ w,
                                               const float* __restrict__ b,
                                               uint* __restrict__ p1) {
    __shared__ uint simg[6720];
    const int tid  = threadIdx.x;
    const int lane = tid & 63;
    const int wv   = tid >> 6;
    const int n0   = blockIdx.x * 2;

    const int colb = lane & 15;
    const int c  = colb & 7, dx = colb >> 3;
    const int g  = lane >> 4;
    const int qr = g;

    half8 bh[3], bl[3];
    #pragma unroll
    for (int ks = 0; ks < 3; ++ks)
        #pragma unroll
        for (int jj = 0; jj < 8; ++jj) {
            int pi = jj >> 1, e = jj & 1;
            int rho = g * 4 + pi;
            float val = 0.f;
            if (rho < 15 && c < 6) {
                int ci = rho / 5, ky = rho % 5;
                int kx = ks * 2 + e - dx;
                if (kx >= 0 && kx < 5) val = w[c * 75 + ci * 25 + ky * 5 + kx];
            }
            _Float16 hh = (_Float16)val;
            bh[ks][jj] = hh;
            bl[ks][jj] = (_Float16)(val - (float)hh);
        }
    const float bias = (c < 6) ? b[c] : 0.f;

    for (int i = tid; i < 1536; i += 256) {
        int im = i / 768;
        int rem = i - im * 768;
        int plane = rem >> 8, rr = (rem & 255) >> 3, f = rem & 7;
        float4 v = *(const float4*)(x + ((size_t)(n0 + im) * 3 + plane) * 1024 + rr * 32 + f * 4);
        _Float16 h0 = (_Float16)v.x, h1 = (_Float16)v.y, h2 = (_Float16)v.z, h3 = (_Float16)v.w;
        _Float16 l0 = (_Float16)(v.x - (float)h0), l1 = (_Float16)(v.y - (float)h1);
        _Float16 l2 = (_Float16)(v.z - (float)h2), l3 = (_Float16)(v.w - (float)h3);
        int base = im * 3360 + plane * 1120 + rr * 35 + f * 2;
        simg[base]      = packhh(h0, h1);
        simg[base + 1]  = packhh(h2, h3);
        simg[base + 16] = packhh(l0, l1);
        simg[base + 17] = packhh(l2, l3);
    }
    // zero pad column 14 of p1 (global; no barrier dependency)
    for (int i = tid; i < 168; i += 256) {
        int im = i / 84, rem = i % 84;
        int cc2 = rem / 14, y = rem % 14;
        p1[(size_t)(n0 + im) * 1260 + cc2 * 210 + y * 15 + 14] = 0u;
    }
    __syncthreads();

    int poff[4];
    #pragma unroll
    for (int pi = 0; pi < 4; ++pi) {
        int rho = g * 4 + pi;
        if (rho > 14) rho = 14;
        poff[pi] = (rho / 5) * 1120 + (rho % 5) * 35;
    }

    for (int t0 = wv; t0 < 50; t0 += 8) {
        const int t1 = (t0 + 4 < 50) ? (t0 + 4) : t0;
        const int im0 = (t0 >= 25) ? 1 : 0, tl0 = t0 - im0 * 25;
        const int im1 = (t1 >= 25) ? 1 : 0, tl1 = t1 - im1 * 25;
        int r0c = tl0 * 16 + colb; if (r0c > 391) r0c = 391;
        int r1c = tl1 * 16 + colb; if (r1c > 391) r1c = 391;
        int qx0 = (r0c * 586) >> 14, yy0 = r0c - qx0 * 28;
        int qx1 = (r1c * 586) >> 14, yy1 = r1c - qx1 * 28;
        const uint* base0 = simg + im0 * 3360 + yy0 * 35 + qx0;
        const uint* base1 = simg + im1 * 3360 + yy1 * 35 + qx1;

        f32x4 A0[2] = {{0.f,0.f,0.f,0.f},{0.f,0.f,0.f,0.f}};
        f32x4 A1[2] = {{0.f,0.f,0.f,0.f},{0.f,0.f,0.f,0.f}};
        int c0 = 0, c1 = 0;
        #pragma unroll
        for (int ks = 0; ks < 3; ++ks) {
            uint h0[4], l0[4], h1[4], l1[4];
            #pragma unroll
            for (int pi = 0; pi < 4; ++pi) {
                const uint* a0p = base0 + poff[pi];
                const uint* a1p = base1 + poff[pi];
                h0[pi] = a0p[ks];  l0[pi] = a0p[16 + ks];
                h1[pi] = a1p[ks];  l1[pi] = a1p[16 + ks];
            }
            uint4 hv0; hv0.x = h0[0]; hv0.y = h0[1]; hv0.z = h0[2]; hv0.w = h0[3];
            uint4 lv0; lv0.x = l0[0]; lv0.y = l0[1]; lv0.z = l0[2]; lv0.w = l0[3];
            uint4 hv1; hv1.x = h1[0]; hv1.y = h1[1]; hv1.z = h1[2]; hv1.w = h1[3];
            uint4 lv1; lv1.x = l1[0]; lv1.y = l1[1]; lv1.z = l1[2]; lv1.w = l1[3];
            half8 ah0 = __builtin_bit_cast(half8, hv0);
            half8 al0 = __builtin_bit_cast(half8, lv0);
            half8 ah1 = __builtin_bit_cast(half8, hv1);
            half8 al1 = __builtin_bit_cast(half8, lv1);
            A0[c0 & 1] = __builtin_amdgcn_mfma_f32_16x16x32_f16(ah0, bh[ks], A0[c0 & 1], 0, 0, 0); ++c0;
            A1[c1 & 1] = __builtin_amdgcn_mfma_f32_16x16x32_f16(ah1, bh[ks], A1[c1 & 1], 0, 0, 0); ++c1;
            A0[c0 & 1] = __builtin_amdgcn_mfma_f32_16x16x32_f16(ah0, bl[ks], A0[c0 & 1], 0, 0, 0); ++c0;
            A1[c1 & 1] = __builtin_amdgcn_mfma_f32_16x16x32_f16(ah1, bl[ks], A1[c1 & 1], 0, 0, 0); ++c1;
            A0[c0 & 1] = __builtin_amdgcn_mfma_f32_16x16x32_f16(al0, bh[ks], A0[c0 & 1], 0, 0, 0); ++c0;
            A1[c1 & 1] = __builtin_amdgcn_mfma_f32_16x16x32_f16(al1, bh[ks], A1[c1 & 1], 0, 0, 0); ++c1;
        }
        {
            f32x4 acc;
            #pragma unroll
            for (int i = 0; i < 4; ++i) acc[i] = A0[0][i] + A0[1][i];
            float p01 = dpp_max8(fmaxf(acc[0], acc[1]));
            float p23 = dpp_max8(fmaxf(acc[2], acc[3]));
            if (dx == 0 && c < 6) {
                uint* outb = p1 + (size_t)(n0 + im0) * 1260 + c * 210;
                int r0 = tl0 * 16 + qr * 4;
                if (r0 + 1 < 392) {
                    int qxa = (r0 * 586) >> 14, ya = r0 - qxa * 28;
                    outb[(ya >> 1) * 15 + qxa] = splitpack(fmaxf(p01 + bias, 0.f));
                }
                int r2 = r0 + 2;
                if (r2 + 1 < 392) {
                    int qxb = (r2 * 586) >> 14, yb = r2 - qxb * 28;
                    outb[(yb >> 1) * 15 + qxb] = splitpack(fmaxf(p23 + bias, 0.f));
                }
            }
        }
        if (t1 != t0) {
            f32x4 acc;
            #pragma unroll
            for (int i = 0; i < 4; ++i) acc[i] = A1[0][i] + A1[1][i];
            float p01 = dpp_max8(fmaxf(acc[0], acc[1]));
            float p23 = dpp_max8(fmaxf(acc[2], acc[3]));
            if (dx == 0 && c < 6) {
                uint* outb = p1 + (size_t)(n0 + im1) * 1260 + c * 210;
                int r0 = tl1 * 16 + qr * 4;
                if (r0 + 1 < 392) {
                    int qxa = (r0 * 586) >> 14, ya = r0 - qxa * 28;
                    outb[(ya >> 1) * 15 + qxa] = splitpack(fmaxf(p01 + bias, 0.f));
                }
                int r2 = r0 + 2;
                if (r2 + 1 < 392) {
                    int qxb = (r2 * 586) >> 14, yb = r2 - qxb * 28;
                    outb[(yb >> 1) * 15 + qxb] = splitpack(fmaxf(p23 + bias, 0.f));
                }
            }
        }
    }
}

// ---------------- conv2: p1 (padded layout) -> p2 fp32; staging = linear uint4 copy ----------------
__global__ __launch_bounds__(256) void k_conv2(const uint* __restrict__ p1,
                                               const float* __restrict__ w,
                                               const float* __restrict__ b,
                                               float* __restrict__ p2) {
    __shared__ __align__(16) uint simg[4 * 1260];
    const int tid  = threadIdx.x;
    const int lane = tid & 63;
    const int wv   = tid >> 6;
    const int n0   = blockIdx.x * 4;
    const int g  = lane >> 4;
    const int cc = lane & 15;
    const int qr = g;

    {   // 4 imgs * 1260 uints = 1260 uint4, straight copy (p1 already padded + col14 zeroed)
        const uint4* pg = (const uint4*)(p1 + (size_t)n0 * 1260);
        uint4* sg = (uint4*)simg;
        for (int i = tid; i < 1260; i += 256) sg[i] = pg[i];
    }

    half8 bh[6], bl[6];
    #pragma unroll
    for (int ks = 0; ks < 6; ++ks)
        #pragma unroll
        for (int jj = 0; jj < 8; ++jj) {
            int pi = jj >> 1, e = jj & 1;
            int rho = (ks / 3) * 16 + g * 4 + pi;
            int kx = (ks % 3) * 2 + e;
            float val = 0.f;
            if (rho < 30 && kx < 5) {
                int ci = rho / 5, ky = rho % 5;
                val = w[cc * 150 + ci * 25 + ky * 5 + kx];
            }
            _Float16 hh = (_Float16)val;
            bh[ks][jj] = hh;
            bl[ks][jj] = (_Float16)(val - (float)hh);
        }
    const float bias = b[cc];
    __syncthreads();

    int poff2[8];
    #pragma unroll
    for (int sp = 0; sp < 8; ++sp) {
        int sel = sp >> 2, pi = sp & 3;
        int rho = sel * 16 + g * 4 + pi;
        if (rho > 29) rho = 29;
        poff2[sp] = (rho / 5) * 210 + (rho % 5) * 15;
    }

    const uint* img = simg + wv * 1260;
    const int qw  = (lane & 15) >> 2;
    const int dy  = (lane >> 1) & 1, dxx = lane & 1;
    float* outb = p2 + (size_t)(n0 + wv) * 400 + cc * 25;

    for (int t = 0; t < 7; ++t) {
        int qa = t * 4 + qw; if (qa > 24) qa = 24;
        int qy = qa / 5, qx = qa % 5;
        int base = (2 * qy + dy) * 15 + (2 * qx + dxx);
        f32x4 acc2[2] = {{0.f,0.f,0.f,0.f},{0.f,0.f,0.f,0.f}};
        int pp = 0;
        #pragma unroll
        for (int sel = 0; sel < 2; ++sel) {
            uint P[4][6];
            #pragma unroll
            for (int pi = 0; pi < 4; ++pi) {
                const uint* ap = img + base + poff2[sel * 4 + pi];
                #pragma unroll
                for (int k = 0; k < 6; ++k) P[pi][k] = ap[k];
            }
            #pragma unroll
            for (int ksr = 0; ksr < 3; ++ksr) {
                const int ks = sel * 3 + ksr;
                uint hu[4], lu[4];
                #pragma unroll
                for (int pi = 0; pi < 4; ++pi) {
                    uint d0 = P[pi][ksr * 2], d1 = P[pi][ksr * 2 + 1];
                    hu[pi] = __builtin_amdgcn_perm(d1, d0, 0x05040100u);
                    lu[pi] = __builtin_amdgcn_perm(d1, d0, 0x07060302u);
                }
                uint4 hv; hv.x = hu[0]; hv.y = hu[1]; hv.z = hu[2]; hv.w = hu[3];
                uint4 lv; lv.x = lu[0]; lv.y = lu[1]; lv.z = lu[2]; lv.w = lu[3];
                half8 ah = __builtin_bit_cast(half8, hv);
                half8 al = __builtin_bit_cast(half8, lv);
                acc2[pp & 1] = __builtin_amdgcn_mfma_f32_16x16x32_f16(ah, bh[ks], acc2[pp & 1], 0, 0, 0); ++pp;
                acc2[pp & 1] = __builtin_amdgcn_mfma_f32_16x16x32_f16(ah, bl[ks], acc2[pp & 1], 0, 0, 0); ++pp;
                acc2[pp & 1] = __builtin_amdgcn_mfma_f32_16x16x32_f16(al, bh[ks], acc2[pp & 1], 0, 0, 0); ++pp;
            }
        }
        int qc = t * 4 + qr;
        if (qc < 25) {
            float m = fmaxf(fmaxf(acc2[0][0] + acc2[1][0], acc2[0][1] + acc2[1][1]),
                            fmaxf(acc2[0][2] + acc2[1][2], acc2[0][3] + acc2[1][3]));
            outb[qc] = fmaxf(m + bias, 0.f);
        }
    }
}

// ---------------- compose: C[e][o][d] = sum_j head_w[o][j]*expert_w[e][j][d] ----------------
__global__ __launch_bounds__(256) void k_compose(const float* __restrict__ ew,
                                                 const float* __restrict__ eb,
                                                 const float* __restrict__ hw,
                                                 float* __restrict__ C,
                                                 float* __restrict__ hb2) {
    __shared__ float shw[840];
    __shared__ float seb[672];
    const int e = blockIdx.x, tid = threadIdx.x;
    for (int i = tid; i < 840; i += 256) shw[i] = hw[i];
    for (int i = tid; i < 672; i += 256) seb[i] = eb[i];
    __syncthreads();
    for (int i = tid; i < 840; i += 256) {
        int o = i / 84, d = i % 84;
        float s = 0.f;
        for (int j = 0; j < 84; ++j)
            s = fmaf(shw[o * 84 + j], ew[((size_t)e * 84 + j) * 84 + d], s);
        C[e * 840 + i] = s;
    }
    if (tid < 10) {
        float s = 0.f;
        for (int j = 0; j < 84; ++j) s = fmaf(shw[tid * 84 + j], seb[e * 84 + j], s);
        hb2[e * 10 + tid] = s;
    }
}

// ---------------- fused fc1+fc2+gate+MoE+head: p2 -> out, h1 stays in LDS ----------------
// Phase1 (fc1): all 512 threads compute; thread (rg=tid>>5, cg=tid&31) owns a 4x4 tile
// (rows rg*4.., cols cg*4..; cg>=30 idle => 480x16 = 7680 outputs exactly).
__global__ __launch_bounds__(512) void k_fc1tail(const float* __restrict__ p2,
                                                 const float* __restrict__ f1w,
                                                 const float* __restrict__ f1b,
                                                 const float* __restrict__ f2w,
                                                 const float* __restrict__ f2b,
                                                 const float* __restrict__ gw,
                                                 const float* __restrict__ Cw,
                                                 const float* __restrict__ hb2,
                                                 const float* __restrict__ headb,
                                                 float* __restrict__ out) {
    __shared__ float region[23872];
    __shared__ float sh1[7680];          // h1: [64][120]
    __shared__ float sfb[84];
    __shared__ int   sei[128];
    const int tid = threadIdx.x;
    const int n0 = blockIdx.x * 64;

    // ---------- phase 1: fc1 ----------
    {
        float* sa  = region;             // [64][100]
        float* swt = region + 6400;      // [120][101]
        const int rg = tid >> 5;         // 0..15 -> rows rg*4+i
        const int cg = tid & 31;         // 0..31 -> cols cg*4+j (cg<30 active)
        float acc[4][4];
        #pragma unroll
        for (int i = 0; i < 4; ++i)
            #pragma unroll
            for (int j = 0; j < 4; ++j) acc[i][j] = 0.f;

        for (int kt = 0; kt < 4; ++kt) {
            __syncthreads();
            for (int i = tid; i < 1600; i += 512) {
                int r = i / 25, k4 = (i % 25) * 4;
                float4 v = *(const float4*)(p2 + (size_t)(n0 + r) * 400 + kt * 100 + k4);
                *(float4*)(sa + r * 100 + k4) = v;
            }
            for (int i = tid; i < 3000; i += 512) {
                int c = i / 25, k4 = (i % 25) * 4;
                float4 v = *(const float4*)(f1w + (size_t)c * 400 + kt * 100 + k4);
                float* d = swt + c * 101 + k4;
                d[0] = v.x; d[1] = v.y; d[2] = v.z; d[3] = v.w;
            }
            __syncthreads();
            if (cg < 30) {
                #pragma unroll 4
                for (int k = 0; k < 100; ++k) {
                    float av[4], wv[4];
                    #pragma unroll
                    for (int i = 0; i < 4; ++i) av[i] = sa[(rg * 4 + i) * 100 + k];
                    #pragma unroll
                    for (int j = 0; j < 4; ++j) wv[j] = swt[(cg * 4 + j) * 101 + k];
                    #pragma unroll
                    for (int i = 0; i < 4; ++i)
                        #pragma unroll
                        for (int j = 0; j < 4; ++j) acc[i][j] = fmaf(av[i], wv[j], acc[i][j]);
                }
            }
        }
        __syncthreads();                 // protect region before phase-2 overwrite
        if (cg < 30) {
            #pragma unroll
            for (int j = 0; j < 4; ++j) {
                const int o = cg * 4 + j;
                const float bo = f1b[o];
                #pragma unroll
                for (int i = 0; i < 4; ++i)
                    sh1[(rg * 4 + i) * 120 + o] = fmaxf(acc[i][j] + bo, 0.f);
            }
        }
    }

    // ---------- phase 2: fc2 + gate + top2 + MoE + head ----------
    float* sfw  = region;
    float* sC   = region + 10164;
    float* sh   = region + 16964;
    float* sgw  = region + 22404;
    float* shb2s= region + 23076;
    float* shb  = region + 23156;
    float* slog = region + 23168;
    float* swt2 = region + 23744;

    for (int i = tid; i < 2520; i += 512) {
        int o = i / 30, k4 = (i % 30) * 4;
        float4 v = *(const float4*)(f2w + (size_t)o * 120 + k4);
        float* d = sfw + o * 121 + k4;
        d[0] = v.x; d[1] = v.y; d[2] = v.z; d[3] = v.w;
    }
    for (int i = tid; i < 6720; i += 512) sC[(i / 84) * 85 + (i % 84)] = Cw[i];
    for (int i = tid; i < 672; i += 512) sgw[i] = gw[i];
    if (tid < 80) shb2s[tid] = hb2[tid];
    if (tid < 10) shb[tid] = headb[tid];
    if (tid < 84) sfb[tid] = f2b[tid];
    __syncthreads();

    for (int i = tid; i < 5376; i += 512) {
        const int t = i / 84, o = i % 84;
        const float* a = sh1 + t * 120;
        const float* wr = sfw + o * 121;
        float s = 0.f;
        #pragma unroll 8
        for (int k = 0; k < 120; ++k) s = fmaf(a[k], wr[k], s);
        sh[t * 85 + o] = fmaxf(s + sfb[o], 0.f);
    }
    __syncthreads();

    {
        const int t = tid / 8, e = tid % 8;
        const float* a = sh + t * 85;
        float s = 0.f;
        #pragma unroll 4
        for (int d = 0; d < 84; ++d) s = fmaf(a[d], sgw[d * 8 + e], s);
        slog[t * 9 + e] = s;
    }
    __syncthreads();

    if (tid < 64) {
        const float* l = slog + tid * 9;
        float m1 = l[0]; int i1 = 0;
        #pragma unroll
        for (int e = 1; e < 8; ++e) if (l[e] > m1) { m1 = l[e]; i1 = e; }
        float m2 = -1e30f; int i2 = 0;
        #pragma unroll
        for (int e = 0; e < 8; ++e) if (e != i1 && l[e] > m2) { m2 = l[e]; i2 = e; }
        const float r = expf(m2 - m1);
        const float inv = 1.f / (1.f + r);
        swt2[tid * 2] = inv; swt2[tid * 2 + 1] = r * inv;
        sei[tid * 2] = i1; sei[tid * 2 + 1] = i2;
    }
    __syncthreads();

    for (int i = tid; i < 640; i += 512) {
        const int t = i / 10, o = i % 10;
        const float* a = sh + t * 85;
        const float w0 = swt2[t * 2], w1 = swt2[t * 2 + 1];
        const int e0 = sei[t * 2], e1 = sei[t * 2 + 1];
        const float* c0 = sC + (e0 * 10 + o) * 85;
        const float* c1 = sC + (e1 * 10 + o) * 85;
        float s0 = 0.f, s1 = 0.f;
        #pragma unroll 4
        for (int d = 0; d < 84; ++d) {
            s0 = fmaf(a[d], c0[d], s0);
            s1 = fmaf(a[d], c1[d], s1);
        }
        out[(size_t)(n0 + t) * 10 + o] =
            shb[o] + w0 * (s0 + shb2s[e0 * 10 + o]) + w1 * (s1 + shb2s[e1 * 10 + o]);
    }
}

extern "C" void kernel_launch(void* const* d_in, const int* in_sizes, int n_in,
                              void* d_out, int out_size, void* d_ws, size_t ws_size,
                              hipStream_t stream) {
    const float* x   = (const float*)d_in[0];
    const float* c1w = (const float*)d_in[1];
    const float* c1b = (const float*)d_in[2];
    const float* c2w = (const float*)d_in[3];
    const float* c2b = (const float*)d_in[4];
    const float* f1w = (const float*)d_in[5];
    const float* f1b = (const float*)d_in[6];
    const float* f2w = (const float*)d_in[7];
    const float* f2b = (const float*)d_in[8];
    const float* gw  = (const float*)d_in[9];
    const float* ew  = (const float*)d_in[10];
    const float* eb  = (const float*)d_in[11];
    const float* hw  = (const float*)d_in[12];
    const float* hb  = (const float*)d_in[13];
    float* out = (float*)d_out;

    const int N = in_sizes[0] / 3072;   // 16384

    float* ws = (float*)d_ws;
    uint*  p1  = (uint*)ws;                    // N*1260 uints (padded conv2 layout)
    float* p2  = ws + (size_t)N * 1260;        // N*400
    float* C   = p2 + (size_t)N * 400;         // 6720
    float* hb2 = C + 6720;                     // 80

    k_conv1<<<N / 2, 256, 0, stream>>>(x, c1w, c1b, p1);
    k_conv2<<<N / 4, 256, 0, stream>>>(p1, c2w, c2b, p2);
    k_compose<<<8, 256, 0, stream>>>(ew, eb, hw, C, hb2);
    k_fc1tail<<<N / 64, 512, 0, stream>>>(p2, f1w, f1b, f2w, f2b, gw, C, hb2, hb, out);
}

// Round 18
// 268.317 us; speedup vs baseline: 1.6483x; 1.0957x over previous
//
#include <hip/hip_runtime.h>
#include <math.h>

typedef _Float16 half8 __attribute__((ext_vector_type(8)));
typedef float f32x4 __attribute__((ext_vector_type(4)));

__device__ inline uint splitpack(float v) {
    _Float16 h = (_Float16)v;
    float r = v - (float)h;
    _Float16 l = (_Float16)r;
    return (uint)__builtin_bit_cast(unsigned short, h) |
           ((uint)__builtin_bit_cast(unsigned short, l) << 16);
}
__device__ inline _Float16 lo16h(uint u) { return __builtin_bit_cast(_Float16, (unsigned short)(u & 0xffffu)); }
__device__ inline _Float16 hi16h(uint u) { return __builtin_bit_cast(_Float16, (unsigned short)(u >> 16)); }
__device__ inline uint packhh(_Float16 a, _Float16 b) {
    return (uint)__builtin_bit_cast(unsigned short, a) |
           ((uint)__builtin_bit_cast(unsigned short, b) << 16);
}
__device__ inline float dpp_max8(float v) {
    int x = __builtin_amdgcn_mov_dpp(__builtin_bit_cast(int, v), 0x128, 0xf, 0xf, true);
    return fmaxf(v, __builtin_bit_cast(float, x));
}

// ---------------- conv1 (round-17 verbatim): x -> p1 packed (padded conv2 layout) ----------------
__global__ __launch_bounds__(256) void k_conv1(const float* __restrict__ x,
                                               const float* __restrict__ w,
                                               const float* __restrict__ b,
                                               uint* __restrict__ p1) {
    __shared__ uint simg[6720];
    const int tid  = threadIdx.x;
    const int lane = tid & 63;
    const int wv   = tid >> 6;
    const int n0   = blockIdx.x * 2;

    const int colb = lane & 15;
    const int c  = colb & 7, dx = colb >> 3;
    const int g  = lane >> 4;
    const int qr = g;

    half8 bh[3], bl[3];
    #pragma unroll
    for (int ks = 0; ks < 3; ++ks)
        #pragma unroll
        for (int jj = 0; jj < 8; ++jj) {
            int pi = jj >> 1, e = jj & 1;
            int rho = g * 4 + pi;
            float val = 0.f;
            if (rho < 15 && c < 6) {
                int ci = rho / 5, ky = rho % 5;
                int kx = ks * 2 + e - dx;
                if (kx >= 0 && kx < 5) val = w[c * 75 + ci * 25 + ky * 5 + kx];
            }
            _Float16 hh = (_Float16)val;
            bh[ks][jj] = hh;
            bl[ks][jj] = (_Float16)(val - (float)hh);
        }
    const float bias = (c < 6) ? b[c] : 0.f;

    for (int i = tid; i < 1536; i += 256) {
        int im = i / 768;
        int rem = i - im * 768;
        int plane = rem >> 8, rr = (rem & 255) >> 3, f = rem & 7;
        float4 v = *(const float4*)(x + ((size_t)(n0 + im) * 3 + plane) * 1024 + rr * 32 + f * 4);
        _Float16 h0 = (_Float16)v.x, h1 = (_Float16)v.y, h2 = (_Float16)v.z, h3 = (_Float16)v.w;
        _Float16 l0 = (_Float16)(v.x - (float)h0), l1 = (_Float16)(v.y - (float)h1);
        _Float16 l2 = (_Float16)(v.z - (float)h2), l3 = (_Float16)(v.w - (float)h3);
        int base = im * 3360 + plane * 1120 + rr * 35 + f * 2;
        simg[base]      = packhh(h0, h1);
        simg[base + 1]  = packhh(h2, h3);
        simg[base + 16] = packhh(l0, l1);
        simg[base + 17] = packhh(l2, l3);
    }
    for (int i = tid; i < 168; i += 256) {
        int im = i / 84, rem = i % 84;
        int cc2 = rem / 14, y = rem % 14;
        p1[(size_t)(n0 + im) * 1260 + cc2 * 210 + y * 15 + 14] = 0u;
    }
    __syncthreads();

    int poff[4];
    #pragma unroll
    for (int pi = 0; pi < 4; ++pi) {
        int rho = g * 4 + pi;
        if (rho > 14) rho = 14;
        poff[pi] = (rho / 5) * 1120 + (rho % 5) * 35;
    }

    for (int t0 = wv; t0 < 50; t0 += 8) {
        const int t1 = (t0 + 4 < 50) ? (t0 + 4) : t0;
        const int im0 = (t0 >= 25) ? 1 : 0, tl0 = t0 - im0 * 25;
        const int im1 = (t1 >= 25) ? 1 : 0, tl1 = t1 - im1 * 25;
        int r0c = tl0 * 16 + colb; if (r0c > 391) r0c = 391;
        int r1c = tl1 * 16 + colb; if (r1c > 391) r1c = 391;
        int qx0 = (r0c * 586) >> 14, yy0 = r0c - qx0 * 28;
        int qx1 = (r1c * 586) >> 14, yy1 = r1c - qx1 * 28;
        const uint* base0 = simg + im0 * 3360 + yy0 * 35 + qx0;
        const uint* base1 = simg + im1 * 3360 + yy1 * 35 + qx1;

        f32x4 A0[2] = {{0.f,0.f,0.f,0.f},{0.f,0.f,0.f,0.f}};
        f32x4 A1[2] = {{0.f,0.f,0.f,0.f},{0.f,0.f,0.f,0.f}};
        int c0 = 0, c1 = 0;
        #pragma unroll
        for (int ks = 0; ks < 3; ++ks) {
            uint h0[4], l0[4], h1[4], l1[4];
            #pragma unroll
            for (int pi = 0; pi < 4; ++pi) {
                const uint* a0p = base0 + poff[pi];
                const uint* a1p = base1 + poff[pi];
                h0[pi] = a0p[ks];  l0[pi] = a0p[16 + ks];
                h1[pi] = a1p[ks];  l1[pi] = a1p[16 + ks];
            }
            uint4 hv0; hv0.x = h0[0]; hv0.y = h0[1]; hv0.z = h0[2]; hv0.w = h0[3];
            uint4 lv0; lv0.x = l0[0]; lv0.y = l0[1]; lv0.z = l0[2]; lv0.w = l0[3];
            uint4 hv1; hv1.x = h1[0]; hv1.y = h1[1]; hv1.z = h1[2]; hv1.w = h1[3];
            uint4 lv1; lv1.x = l1[0]; lv1.y = l1[1]; lv1.z = l1[2]; lv1.w = l1[3];
            half8 ah0 = __builtin_bit_cast(half8, hv0);
            half8 al0 = __builtin_bit_cast(half8, lv0);
            half8 ah1 = __builtin_bit_cast(half8, hv1);
            half8 al1 = __builtin_bit_cast(half8, lv1);
            A0[c0 & 1] = __builtin_amdgcn_mfma_f32_16x16x32_f16(ah0, bh[ks], A0[c0 & 1], 0, 0, 0); ++c0;
            A1[c1 & 1] = __builtin_amdgcn_mfma_f32_16x16x32_f16(ah1, bh[ks], A1[c1 & 1], 0, 0, 0); ++c1;
            A0[c0 & 1] = __builtin_amdgcn_mfma_f32_16x16x32_f16(ah0, bl[ks], A0[c0 & 1], 0, 0, 0); ++c0;
            A1[c1 & 1] = __builtin_amdgcn_mfma_f32_16x16x32_f16(ah1, bl[ks], A1[c1 & 1], 0, 0, 0); ++c1;
            A0[c0 & 1] = __builtin_amdgcn_mfma_f32_16x16x32_f16(al0, bh[ks], A0[c0 & 1], 0, 0, 0); ++c0;
            A1[c1 & 1] = __builtin_amdgcn_mfma_f32_16x16x32_f16(al1, bh[ks], A1[c1 & 1], 0, 0, 0); ++c1;
        }
        {
            f32x4 acc;
            #pragma unroll
            for (int i = 0; i < 4; ++i) acc[i] = A0[0][i] + A0[1][i];
            float p01 = dpp_max8(fmaxf(acc[0], acc[1]));
            float p23 = dpp_max8(fmaxf(acc[2], acc[3]));
            if (dx == 0 && c < 6) {
                uint* outb = p1 + (size_t)(n0 + im0) * 1260 + c * 210;
                int r0 = tl0 * 16 + qr * 4;
                if (r0 + 1 < 392) {
                    int qxa = (r0 * 586) >> 14, ya = r0 - qxa * 28;
                    outb[(ya >> 1) * 15 + qxa] = splitpack(fmaxf(p01 + bias, 0.f));
                }
                int r2 = r0 + 2;
                if (r2 + 1 < 392) {
                    int qxb = (r2 * 586) >> 14, yb = r2 - qxb * 28;
                    outb[(yb >> 1) * 15 + qxb] = splitpack(fmaxf(p23 + bias, 0.f));
                }
            }
        }
        if (t1 != t0) {
            f32x4 acc;
            #pragma unroll
            for (int i = 0; i < 4; ++i) acc[i] = A1[0][i] + A1[1][i];
            float p01 = dpp_max8(fmaxf(acc[0], acc[1]));
            float p23 = dpp_max8(fmaxf(acc[2], acc[3]));
            if (dx == 0 && c < 6) {
                uint* outb = p1 + (size_t)(n0 + im1) * 1260 + c * 210;
                int r0 = tl1 * 16 + qr * 4;
                if (r0 + 1 < 392) {
                    int qxa = (r0 * 586) >> 14, ya = r0 - qxa * 28;
                    outb[(ya >> 1) * 15 + qxa] = splitpack(fmaxf(p01 + bias, 0.f));
                }
                int r2 = r0 + 2;
                if (r2 + 1 < 392) {
                    int qxb = (r2 * 586) >> 14, yb = r2 - qxb * 28;
                    outb[(yb >> 1) * 15 + qxb] = splitpack(fmaxf(p23 + bias, 0.f));
                }
            }
        }
    }
}

// ---------------- conv2 (round-17 verbatim): p1 (padded) -> p2 fp32 ----------------
__global__ __launch_bounds__(256) void k_conv2(const uint* __restrict__ p1,
                                               const float* __restrict__ w,
                                               const float* __restrict__ b,
                                               float* __restrict__ p2) {
    __shared__ __align__(16) uint simg[4 * 1260];
    const int tid  = threadIdx.x;
    const int lane = tid & 63;
    const int wv   = tid >> 6;
    const int n0   = blockIdx.x * 4;
    const int g  = lane >> 4;
    const int cc = lane & 15;
    const int qr = g;

    {
        const uint4* pg = (const uint4*)(p1 + (size_t)n0 * 1260);
        uint4* sg = (uint4*)simg;
        for (int i = tid; i < 1260; i += 256) sg[i] = pg[i];
    }

    half8 bh[6], bl[6];
    #pragma unroll
    for (int ks = 0; ks < 6; ++ks)
        #pragma unroll
        for (int jj = 0; jj < 8; ++jj) {
            int pi = jj >> 1, e = jj & 1;
            int rho = (ks / 3) * 16 + g * 4 + pi;
            int kx = (ks % 3) * 2 + e;
            float val = 0.f;
            if (rho < 30 && kx < 5) {
                int ci = rho / 5, ky = rho % 5;
                val = w[cc * 150 + ci * 25 + ky * 5 + kx];
            }
            _Float16 hh = (_Float16)val;
            bh[ks][jj] = hh;
            bl[ks][jj] = (_Float16)(val - (float)hh);
        }
    const float bias = b[cc];
    __syncthreads();

    int poff2[8];
    #pragma unroll
    for (int sp = 0; sp < 8; ++sp) {
        int sel = sp >> 2, pi = sp & 3;
        int rho = sel * 16 + g * 4 + pi;
        if (rho > 29) rho = 29;
        poff2[sp] = (rho / 5) * 210 + (rho % 5) * 15;
    }

    const uint* img = simg + wv * 1260;
    const int qw  = (lane & 15) >> 2;
    const int dy  = (lane >> 1) & 1, dxx = lane & 1;
    float* outb = p2 + (size_t)(n0 + wv) * 400 + cc * 25;

    for (int t = 0; t < 7; ++t) {
        int qa = t * 4 + qw; if (qa > 24) qa = 24;
        int qy = qa / 5, qx = qa % 5;
        int base = (2 * qy + dy) * 15 + (2 * qx + dxx);
        f32x4 acc2[2] = {{0.f,0.f,0.f,0.f},{0.f,0.f,0.f,0.f}};
        int pp = 0;
        #pragma unroll
        for (int sel = 0; sel < 2; ++sel) {
            uint P[4][6];
            #pragma unroll
            for (int pi = 0; pi < 4; ++pi) {
                const uint* ap = img + base + poff2[sel * 4 + pi];
                #pragma unroll
                for (int k = 0; k < 6; ++k) P[pi][k] = ap[k];
            }
            #pragma unroll
            for (int ksr = 0; ksr < 3; ++ksr) {
                const int ks = sel * 3 + ksr;
                uint hu[4], lu[4];
                #pragma unroll
                for (int pi = 0; pi < 4; ++pi) {
                    uint d0 = P[pi][ksr * 2], d1 = P[pi][ksr * 2 + 1];
                    hu[pi] = __builtin_amdgcn_perm(d1, d0, 0x05040100u);
                    lu[pi] = __builtin_amdgcn_perm(d1, d0, 0x07060302u);
                }
                uint4 hv; hv.x = hu[0]; hv.y = hu[1]; hv.z = hu[2]; hv.w = hu[3];
                uint4 lv; lv.x = lu[0]; lv.y = lu[1]; lv.z = lu[2]; lv.w = lu[3];
                half8 ah = __builtin_bit_cast(half8, hv);
                half8 al = __builtin_bit_cast(half8, lv);
                acc2[pp & 1] = __builtin_amdgcn_mfma_f32_16x16x32_f16(ah, bh[ks], acc2[pp & 1], 0, 0, 0); ++pp;
                acc2[pp & 1] = __builtin_amdgcn_mfma_f32_16x16x32_f16(ah, bl[ks], acc2[pp & 1], 0, 0, 0); ++pp;
                acc2[pp & 1] = __builtin_amdgcn_mfma_f32_16x16x32_f16(al, bh[ks], acc2[pp & 1], 0, 0, 0); ++pp;
            }
        }
        int qc = t * 4 + qr;
        if (qc < 25) {
            float m = fmaxf(fmaxf(acc2[0][0] + acc2[1][0], acc2[0][1] + acc2[1][1]),
                            fmaxf(acc2[0][2] + acc2[1][2], acc2[0][3] + acc2[1][3]));
            outb[qc] = fmaxf(m + bias, 0.f);
        }
    }
}

// ---------------- compose: C[e][o][d] = sum_j head_w[o][j]*expert_w[e][j][d] ----------------
__global__ __launch_bounds__(256) void k_compose(const float* __restrict__ ew,
                                                 const float* __restrict__ eb,
                                                 const float* __restrict__ hw,
                                                 float* __restrict__ C,
                                                 float* __restrict__ hb2) {
    __shared__ float shw[840];
    __shared__ float seb[672];
    const int e = blockIdx.x, tid = threadIdx.x;
    for (int i = tid; i < 840; i += 256) shw[i] = hw[i];
    for (int i = tid; i < 672; i += 256) seb[i] = eb[i];
    __syncthreads();
    for (int i = tid; i < 840; i += 256) {
        int o = i / 84, d = i % 84;
        float s = 0.f;
        for (int j = 0; j < 84; ++j)
            s = fmaf(shw[o * 84 + j], ew[((size_t)e * 84 + j) * 84 + d], s);
        C[e * 840 + i] = s;
    }
    if (tid < 10) {
        float s = 0.f;
        for (int j = 0; j < 84; ++j) s = fmaf(shw[tid * 84 + j], seb[e * 84 + j], s);
        hb2[e * 10 + tid] = s;
    }
}

// ---------------- fused fc1(MFMA)+fc2+gate+MoE+head: p2 -> out ----------------
// Phase1: C[out][token] = f1w x p2^T via split-fp16 MFMA. Wave wv = M-tile (outs wv*16..),
// N-tiles = 4 token groups. K=400 in 4 chunks of 128 (slices {4,4,4,1}).
// p2 staged per-chunk as SoA half-planes h[64][136]/l[64][136] (row 272B -> 2-way b128 reads).
// A-fragments per-lane from global f1w (groups of 8 k are all-real or all-fake since 400%8==0).
// sh1 stride 121 (conflict-free epilogue writes).
__global__ __launch_bounds__(512) void k_fc1tail(const float* __restrict__ p2,
                                                 const float* __restrict__ f1w,
                                                 const float* __restrict__ f1b,
                                                 const float* __restrict__ f2w,
                                                 const float* __restrict__ f2b,
                                                 const float* __restrict__ gw,
                                                 const float* __restrict__ Cw,
                                                 const float* __restrict__ hb2,
                                                 const float* __restrict__ headb,
                                                 float* __restrict__ out) {
    __shared__ __align__(16) float region[23872];
    __shared__ float sh1[7744];          // h1: [64][121]
    __shared__ float sfb[84];
    __shared__ int   sei[128];
    const int tid = threadIdx.x;
    const int n0 = blockIdx.x * 64;

    // ---------- phase 1: fc1 via MFMA ----------
    {
        uint* hplu = (uint*)region;              // h-plane: row stride 68 uints (136 halves)
        const int lane = tid & 63;
        const int wvv  = tid >> 6;
        const int cc = lane & 15, g = lane >> 4;
        const int outg = wvv * 16 + cc;          // A-row (out channel) this lane feeds
        f32x4 acc[4] = {{0.f,0.f,0.f,0.f},{0.f,0.f,0.f,0.f},{0.f,0.f,0.f,0.f},{0.f,0.f,0.f,0.f}};

        for (int kc = 0; kc < 4; ++kc) {
            __syncthreads();
            // stage chunk: 4096 float-pairs -> h/l planes
            for (int p = tid; p < 4096; p += 512) {
                int row = p >> 6, pk = (p & 63) * 2;
                int k = kc * 128 + pk;
                float vx = 0.f, vy = 0.f;
                if (k < 400) {
                    float2 v = *(const float2*)(p2 + (size_t)(n0 + row) * 400 + k);
                    vx = v.x; vy = v.y;
                }
                _Float16 h0 = (_Float16)vx, h1 = (_Float16)vy;
                _Float16 l0 = (_Float16)(vx - (float)h0), l1 = (_Float16)(vy - (float)h1);
                hplu[row * 68 + (pk >> 1)]        = packhh(h0, h1);
                hplu[4352 + row * 68 + (pk >> 1)] = packhh(l0, l1);
            }
            __syncthreads();
            const int nslice = (kc < 3) ? 4 : 1;
            for (int s = 0; s < nslice; ++s) {
                const int kbase = kc * 128 + s * 32 + g * 8;
                float fa[8] = {0.f,0.f,0.f,0.f,0.f,0.f,0.f,0.f};
                if (outg < 120 && kbase + 7 < 400) {
                    float4 va = *(const float4*)(f1w + (size_t)outg * 400 + kbase);
                    float4 vb = *(const float4*)(f1w + (size_t)outg * 400 + kbase + 4);
                    fa[0]=va.x; fa[1]=va.y; fa[2]=va.z; fa[3]=va.w;
                    fa[4]=vb.x; fa[5]=vb.y; fa[6]=vb.z; fa[7]=vb.w;
                }
                half8 ah, al;
                #pragma unroll
                for (int j = 0; j < 8; ++j) {
                    _Float16 h = (_Float16)fa[j];
                    ah[j] = h;
                    al[j] = (_Float16)(fa[j] - (float)h);
                }
                #pragma unroll
                for (int nt = 0; nt < 4; ++nt) {
                    const int row = nt * 16 + cc;
                    uint4 hv = *(const uint4*)(hplu + row * 68 + s * 16 + g * 4);
                    uint4 lv = *(const uint4*)(hplu + 4352 + row * 68 + s * 16 + g * 4);
                    half8 bh8 = __builtin_bit_cast(half8, hv);
                    half8 bl8 = __builtin_bit_cast(half8, lv);
                    acc[nt] = __builtin_amdgcn_mfma_f32_16x16x32_f16(ah, bh8, acc[nt], 0, 0, 0);
                    acc[nt] = __builtin_amdgcn_mfma_f32_16x16x32_f16(ah, bl8, acc[nt], 0, 0, 0);
                    acc[nt] = __builtin_amdgcn_mfma_f32_16x16x32_f16(al, bh8, acc[nt], 0, 0, 0);
                }
            }
        }
        __syncthreads();                 // done reading region (before phase-2 overwrite)
        // epilogue: C row = g*4+i (out local), col = cc (token local); o independent of nt
        float bo[4]; int ov[4];
        #pragma unroll
        for (int i2 = 0; i2 < 4; ++i2) {
            ov[i2] = wvv * 16 + g * 4 + i2;
            bo[i2] = (ov[i2] < 120) ? f1b[ov[i2]] : 0.f;
        }
        #pragma unroll
        for (int nt = 0; nt < 4; ++nt) {
            const int token = nt * 16 + cc;
            #pragma unroll
            for (int i2 = 0; i2 < 4; ++i2) {
                if (ov[i2] < 120)
                    sh1[token * 121 + ov[i2]] = fmaxf(acc[nt][i2] + bo[i2], 0.f);
            }
        }
    }

    // ---------- phase 2: fc2 + gate + top2 + MoE + head ----------
    float* sfw  = region;
    float* sC   = region + 10164;
    float* sh   = region + 16964;
    float* sgw  = region + 22404;
    float* shb2s= region + 23076;
    float* shb  = region + 23156;
    float* slog = region + 23168;
    float* swt2 = region + 23744;

    for (int i = tid; i < 2520; i += 512) {
        int o = i / 30, k4 = (i % 30) * 4;
        float4 v = *(const float4*)(f2w + (size_t)o * 120 + k4);
        float* d = sfw + o * 121 + k4;
        d[0] = v.x; d[1] = v.y; d[2] = v.z; d[3] = v.w;
    }
    for (int i = tid; i < 6720; i += 512) sC[(i / 84) * 85 + (i % 84)] = Cw[i];
    for (int i = tid; i < 672; i += 512) sgw[i] = gw[i];
    if (tid < 80) shb2s[tid] = hb2[tid];
    if (tid < 10) shb[tid] = headb[tid];
    if (tid < 84) sfb[tid] = f2b[tid];
    __syncthreads();

    for (int i = tid; i < 5376; i += 512) {
        const int t = i / 84, o = i % 84;
        const float* a = sh1 + t * 121;
        const float* wr = sfw + o * 121;
        float s = 0.f;
        #pragma unroll 8
        for (int k = 0; k < 120; ++k) s = fmaf(a[k], wr[k], s);
        sh[t * 85 + o] = fmaxf(s + sfb[o], 0.f);
    }
    __syncthreads();

    {
        const int t = tid / 8, e = tid % 8;
        const float* a = sh + t * 85;
        float s = 0.f;
        #pragma unroll 4
        for (int d = 0; d < 84; ++d) s = fmaf(a[d], sgw[d * 8 + e], s);
        slog[t * 9 + e] = s;
    }
    __syncthreads();

    if (tid < 64) {
        const float* l = slog + tid * 9;
        float m1 = l[0]; int i1 = 0;
        #pragma unroll
        for (int e = 1; e < 8; ++e) if (l[e] > m1) { m1 = l[e]; i1 = e; }
        float m2 = -1e30f; int i2 = 0;
        #pragma unroll
        for (int e = 0; e < 8; ++e) if (e != i1 && l[e] > m2) { m2 = l[e]; i2 = e; }
        const float r = expf(m2 - m1);
        const float inv = 1.f / (1.f + r);
        swt2[tid * 2] = inv; swt2[tid * 2 + 1] = r * inv;
        sei[tid * 2] = i1; sei[tid * 2 + 1] = i2;
    }
    __syncthreads();

    for (int i = tid; i < 640; i += 512) {
        const int t = i / 10, o = i % 10;
        const float* a = sh + t * 85;
        const float w0 = swt2[t * 2], w1 = swt2[t * 2 + 1];
        const int e0 = sei[t * 2], e1 = sei[t * 2 + 1];
        const float* c0 = sC + (e0 * 10 + o) * 85;
        const float* c1 = sC + (e1 * 10 + o) * 85;
        float s0 = 0.f, s1 = 0.f;
        #pragma unroll 4
        for (int d = 0; d < 84; ++d) {
            s0 = fmaf(a[d], c0[d], s0);
            s1 = fmaf(a[d], c1[d], s1);
        }
        out[(size_t)(n0 + t) * 10 + o] =
            shb[o] + w0 * (s0 + shb2s[e0 * 10 + o]) + w1 * (s1 + shb2s[e1 * 10 + o]);
    }
}

extern "C" void kernel_launch(void* const* d_in, const int* in_sizes, int n_in,
                              void* d_out, int out_size, void* d_ws, size_t ws_size,
                              hipStream_t stream) {
    const float* x   = (const float*)d_in[0];
    const float* c1w = (const float*)d_in[1];
    const float* c1b = (const float*)d_in[2];
    const float* c2w = (const float*)d_in[3];
    const float* c2b = (const float*)d_in[4];
    const float* f1w = (const float*)d_in[5];
    const float* f1b = (const float*)d_in[6];
    const float* f2w = (const float*)d_in[7];
    const float* f2b = (const float*)d_in[8];
    const float* gw  = (const float*)d_in[9];
    const float* ew  = (const float*)d_in[10];
    const float* eb  = (const float*)d_in[11];
    const float* hw  = (const float*)d_in[12];
    const float* hb  = (const float*)d_in[13];
    float* out = (float*)d_out;

    const int N = in_sizes[0] / 3072;   // 16384

    float* ws = (float*)d_ws;
    uint*  p1  = (uint*)ws;                    // N*1260 uints (padded conv2 layout)
    float* p2  = ws + (size_t)N * 1260;        // N*400
    float* C   = p2 + (size_t)N * 400;         // 6720
    float* hb2 = C + 6720;                     // 80

    k_conv1<<<N / 2, 256, 0, stream>>>(x, c1w, c1b, p1);
    k_conv2<<<N / 4, 256, 0, stream>>>(p1, c2w, c2b, p2);
    k_compose<<<8, 256, 0, stream>>>(ew, eb, hw, C, hb2);
    k_fc1tail<<<N / 64, 512, 0, stream>>>(p2, f1w, f1b, f2w, f2b, gw, C, hb2, hb, out);
}

// Round 19
// 261.783 us; speedup vs baseline: 1.6895x; 1.0250x over previous
//
#include <hip/hip_runtime.h>
#include <math.h>

typedef _Float16 half8 __attribute__((ext_vector_type(8)));
typedef float f32x4 __attribute__((ext_vector_type(4)));

__device__ inline uint splitpack(float v) {
    _Float16 h = (_Float16)v;
    float r = v - (float)h;
    _Float16 l = (_Float16)r;
    return (uint)__builtin_bit_cast(unsigned short, h) |
           ((uint)__builtin_bit_cast(unsigned short, l) << 16);
}
__device__ inline _Float16 lo16h(uint u) { return __builtin_bit_cast(_Float16, (unsigned short)(u & 0xffffu)); }
__device__ inline _Float16 hi16h(uint u) { return __builtin_bit_cast(_Float16, (unsigned short)(u >> 16)); }
__device__ inline uint packhh(_Float16 a, _Float16 b) {
    return (uint)__builtin_bit_cast(unsigned short, a) |
           ((uint)__builtin_bit_cast(unsigned short, b) << 16);
}
__device__ inline float dpp_max8(float v) {
    int x = __builtin_amdgcn_mov_dpp(__builtin_bit_cast(int, v), 0x128, 0xf, 0xf, true);
    return fmaxf(v, __builtin_bit_cast(float, x));
}

// ---------------- conv1: x -> p1 packed, COMPACT layout [N][6][196] (dense-line writes) ----------------
__global__ __launch_bounds__(256) void k_conv1(const float* __restrict__ x,
                                               const float* __restrict__ w,
                                               const float* __restrict__ b,
                                               uint* __restrict__ p1) {
    __shared__ uint simg[6720];
    const int tid  = threadIdx.x;
    const int lane = tid & 63;
    const int wv   = tid >> 6;
    const int n0   = blockIdx.x * 2;

    const int colb = lane & 15;
    const int c  = colb & 7, dx = colb >> 3;
    const int g  = lane >> 4;
    const int qr = g;

    half8 bh[3], bl[3];
    #pragma unroll
    for (int ks = 0; ks < 3; ++ks)
        #pragma unroll
        for (int jj = 0; jj < 8; ++jj) {
            int pi = jj >> 1, e = jj & 1;
            int rho = g * 4 + pi;
            float val = 0.f;
            if (rho < 15 && c < 6) {
                int ci = rho / 5, ky = rho % 5;
                int kx = ks * 2 + e - dx;
                if (kx >= 0 && kx < 5) val = w[c * 75 + ci * 25 + ky * 5 + kx];
            }
            _Float16 hh = (_Float16)val;
            bh[ks][jj] = hh;
            bl[ks][jj] = (_Float16)(val - (float)hh);
        }
    const float bias = (c < 6) ? b[c] : 0.f;

    for (int i = tid; i < 1536; i += 256) {
        int im = i / 768;
        int rem = i - im * 768;
        int plane = rem >> 8, rr = (rem & 255) >> 3, f = rem & 7;
        float4 v = *(const float4*)(x + ((size_t)(n0 + im) * 3 + plane) * 1024 + rr * 32 + f * 4);
        _Float16 h0 = (_Float16)v.x, h1 = (_Float16)v.y, h2 = (_Float16)v.z, h3 = (_Float16)v.w;
        _Float16 l0 = (_Float16)(v.x - (float)h0), l1 = (_Float16)(v.y - (float)h1);
        _Float16 l2 = (_Float16)(v.z - (float)h2), l3 = (_Float16)(v.w - (float)h3);
        int base = im * 3360 + plane * 1120 + rr * 35 + f * 2;
        simg[base]      = packhh(h0, h1);
        simg[base + 1]  = packhh(h2, h3);
        simg[base + 16] = packhh(l0, l1);
        simg[base + 17] = packhh(l2, l3);
    }
    __syncthreads();

    int poff[4];
    #pragma unroll
    for (int pi = 0; pi < 4; ++pi) {
        int rho = g * 4 + pi;
        if (rho > 14) rho = 14;
        poff[pi] = (rho / 5) * 1120 + (rho % 5) * 35;
    }

    for (int t0 = wv; t0 < 50; t0 += 8) {
        const int t1 = (t0 + 4 < 50) ? (t0 + 4) : t0;
        const int im0 = (t0 >= 25) ? 1 : 0, tl0 = t0 - im0 * 25;
        const int im1 = (t1 >= 25) ? 1 : 0, tl1 = t1 - im1 * 25;
        int r0c = tl0 * 16 + colb; if (r0c > 391) r0c = 391;
        int r1c = tl1 * 16 + colb; if (r1c > 391) r1c = 391;
        int qx0 = (r0c * 586) >> 14, yy0 = r0c - qx0 * 28;
        int qx1 = (r1c * 586) >> 14, yy1 = r1c - qx1 * 28;
        const uint* base0 = simg + im0 * 3360 + yy0 * 35 + qx0;
        const uint* base1 = simg + im1 * 3360 + yy1 * 35 + qx1;

        f32x4 A0[2] = {{0.f,0.f,0.f,0.f},{0.f,0.f,0.f,0.f}};
        f32x4 A1[2] = {{0.f,0.f,0.f,0.f},{0.f,0.f,0.f,0.f}};
        int c0 = 0, c1 = 0;
        #pragma unroll
        for (int ks = 0; ks < 3; ++ks) {
            uint h0[4], l0[4], h1[4], l1[4];
            #pragma unroll
            for (int pi = 0; pi < 4; ++pi) {
                const uint* a0p = base0 + poff[pi];
                const uint* a1p = base1 + poff[pi];
                h0[pi] = a0p[ks];  l0[pi] = a0p[16 + ks];
                h1[pi] = a1p[ks];  l1[pi] = a1p[16 + ks];
            }
            uint4 hv0; hv0.x = h0[0]; hv0.y = h0[1]; hv0.z = h0[2]; hv0.w = h0[3];
            uint4 lv0; lv0.x = l0[0]; lv0.y = l0[1]; lv0.z = l0[2]; lv0.w = l0[3];
            uint4 hv1; hv1.x = h1[0]; hv1.y = h1[1]; hv1.z = h1[2]; hv1.w = h1[3];
            uint4 lv1; lv1.x = l1[0]; lv1.y = l1[1]; lv1.z = l1[2]; lv1.w = l1[3];
            half8 ah0 = __builtin_bit_cast(half8, hv0);
            half8 al0 = __builtin_bit_cast(half8, lv0);
            half8 ah1 = __builtin_bit_cast(half8, hv1);
            half8 al1 = __builtin_bit_cast(half8, lv1);
            A0[c0 & 1] = __builtin_amdgcn_mfma_f32_16x16x32_f16(ah0, bh[ks], A0[c0 & 1], 0, 0, 0); ++c0;
            A1[c1 & 1] = __builtin_amdgcn_mfma_f32_16x16x32_f16(ah1, bh[ks], A1[c1 & 1], 0, 0, 0); ++c1;
            A0[c0 & 1] = __builtin_amdgcn_mfma_f32_16x16x32_f16(ah0, bl[ks], A0[c0 & 1], 0, 0, 0); ++c0;
            A1[c1 & 1] = __builtin_amdgcn_mfma_f32_16x16x32_f16(ah1, bl[ks], A1[c1 & 1], 0, 0, 0); ++c1;
            A0[c0 & 1] = __builtin_amdgcn_mfma_f32_16x16x32_f16(al0, bh[ks], A0[c0 & 1], 0, 0, 0); ++c0;
            A1[c1 & 1] = __builtin_amdgcn_mfma_f32_16x16x32_f16(al1, bh[ks], A1[c1 & 1], 0, 0, 0); ++c1;
        }
        {
            f32x4 acc;
            #pragma unroll
            for (int i = 0; i < 4; ++i) acc[i] = A0[0][i] + A0[1][i];
            float p01 = dpp_max8(fmaxf(acc[0], acc[1]));
            float p23 = dpp_max8(fmaxf(acc[2], acc[3]));
            if (dx == 0 && c < 6) {
                uint* outb = p1 + (size_t)(n0 + im0) * 1176 + c * 196;
                int r0 = tl0 * 16 + qr * 4;
                if (r0 + 1 < 392) {
                    int qxa = (r0 * 586) >> 14, ya = r0 - qxa * 28;
                    outb[(ya >> 1) * 14 + qxa] = splitpack(fmaxf(p01 + bias, 0.f));
                }
                int r2 = r0 + 2;
                if (r2 + 1 < 392) {
                    int qxb = (r2 * 586) >> 14, yb = r2 - qxb * 28;
                    outb[(yb >> 1) * 14 + qxb] = splitpack(fmaxf(p23 + bias, 0.f));
                }
            }
        }
        if (t1 != t0) {
            f32x4 acc;
            #pragma unroll
            for (int i = 0; i < 4; ++i) acc[i] = A1[0][i] + A1[1][i];
            float p01 = dpp_max8(fmaxf(acc[0], acc[1]));
            float p23 = dpp_max8(fmaxf(acc[2], acc[3]));
            if (dx == 0 && c < 6) {
                uint* outb = p1 + (size_t)(n0 + im1) * 1176 + c * 196;
                int r0 = tl1 * 16 + qr * 4;
                if (r0 + 1 < 392) {
                    int qxa = (r0 * 586) >> 14, ya = r0 - qxa * 28;
                    outb[(ya >> 1) * 14 + qxa] = splitpack(fmaxf(p01 + bias, 0.f));
                }
                int r2 = r0 + 2;
                if (r2 + 1 < 392) {
                    int qxb = (r2 * 586) >> 14, yb = r2 - qxb * 28;
                    outb[(yb >> 1) * 14 + qxb] = splitpack(fmaxf(p23 + bias, 0.f));
                }
            }
        }
    }
}

// ---------------- conv2: compact p1 -> p2 fp32; linear staging, stride-14 LDS rows ----------------
// kx=5 pad slots (B=0) read "col 14" = next row's col 0 (real finite data x 0) — deterministic.
// Final one-past-end read (last img, last row) lands in the zeroed 8-dword tail.
__global__ __launch_bounds__(256) void k_conv2(const uint* __restrict__ p1,
                                               const float* __restrict__ w,
                                               const float* __restrict__ b,
                                               float* __restrict__ p2) {
    __shared__ __align__(16) uint simg[4 * 1176 + 8];
    const int tid  = threadIdx.x;
    const int lane = tid & 63;
    const int wv   = tid >> 6;
    const int n0   = blockIdx.x * 4;
    const int g  = lane >> 4;
    const int cc = lane & 15;
    const int qr = g;

    {   // 4 imgs * 1176 uints = 1176 uint4, straight copy
        const uint4* pg = (const uint4*)(p1 + (size_t)n0 * 1176);
        uint4* sg = (uint4*)simg;
        for (int i = tid; i < 1176; i += 256) sg[i] = pg[i];
        if (tid < 8) simg[4704 + tid] = 0u;   // zero tail for one-past-end pad reads
    }

    half8 bh[6], bl[6];
    #pragma unroll
    for (int ks = 0; ks < 6; ++ks)
        #pragma unroll
        for (int jj = 0; jj < 8; ++jj) {
            int pi = jj >> 1, e = jj & 1;
            int rho = (ks / 3) * 16 + g * 4 + pi;
            int kx = (ks % 3) * 2 + e;
            float val = 0.f;
            if (rho < 30 && kx < 5) {
                int ci = rho / 5, ky = rho % 5;
                val = w[cc * 150 + ci * 25 + ky * 5 + kx];
            }
            _Float16 hh = (_Float16)val;
            bh[ks][jj] = hh;
            bl[ks][jj] = (_Float16)(val - (float)hh);
        }
    const float bias = b[cc];
    __syncthreads();

    int poff2[8];
    #pragma unroll
    for (int sp = 0; sp < 8; ++sp) {
        int sel = sp >> 2, pi = sp & 3;
        int rho = sel * 16 + g * 4 + pi;
        if (rho > 29) rho = 29;
        poff2[sp] = (rho / 5) * 196 + (rho % 5) * 14;
    }

    const uint* img = simg + wv * 1176;
    const int qw  = (lane & 15) >> 2;
    const int dy  = (lane >> 1) & 1, dxx = lane & 1;
    float* outb = p2 + (size_t)(n0 + wv) * 400 + cc * 25;

    for (int t = 0; t < 7; ++t) {
        int qa = t * 4 + qw; if (qa > 24) qa = 24;
        int qy = qa / 5, qx = qa % 5;
        int base = (2 * qy + dy) * 14 + (2 * qx + dxx);
        f32x4 acc2[2] = {{0.f,0.f,0.f,0.f},{0.f,0.f,0.f,0.f}};
        int pp = 0;
        #pragma unroll
        for (int sel = 0; sel < 2; ++sel) {
            uint P[4][6];
            #pragma unroll
            for (int pi = 0; pi < 4; ++pi) {
                const uint* ap = img + base + poff2[sel * 4 + pi];
                #pragma unroll
                for (int k = 0; k < 6; ++k) P[pi][k] = ap[k];  // 3x ds_read2_b32
            }
            #pragma unroll
            for (int ksr = 0; ksr < 3; ++ksr) {
                const int ks = sel * 3 + ksr;
                uint hu[4], lu[4];
                #pragma unroll
                for (int pi = 0; pi < 4; ++pi) {
                    uint d0 = P[pi][ksr * 2], d1 = P[pi][ksr * 2 + 1];
                    hu[pi] = __builtin_amdgcn_perm(d1, d0, 0x05040100u);
                    lu[pi] = __builtin_amdgcn_perm(d1, d0, 0x07060302u);
                }
                uint4 hv; hv.x = hu[0]; hv.y = hu[1]; hv.z = hu[2]; hv.w = hu[3];
                uint4 lv; lv.x = lu[0]; lv.y = lu[1]; lv.z = lu[2]; lv.w = lu[3];
                half8 ah = __builtin_bit_cast(half8, hv);
                half8 al = __builtin_bit_cast(half8, lv);
                acc2[pp & 1] = __builtin_amdgcn_mfma_f32_16x16x32_f16(ah, bh[ks], acc2[pp & 1], 0, 0, 0); ++pp;
                acc2[pp & 1] = __builtin_amdgcn_mfma_f32_16x16x32_f16(ah, bl[ks], acc2[pp & 1], 0, 0, 0); ++pp;
                acc2[pp & 1] = __builtin_amdgcn_mfma_f32_16x16x32_f16(al, bh[ks], acc2[pp & 1], 0, 0, 0); ++pp;
            }
        }
        int qc = t * 4 + qr;
        if (qc < 25) {
            float m = fmaxf(fmaxf(acc2[0][0] + acc2[1][0], acc2[0][1] + acc2[1][1]),
                            fmaxf(acc2[0][2] + acc2[1][2], acc2[0][3] + acc2[1][3]));
            outb[qc] = fmaxf(m + bias, 0.f);
        }
    }
}

// ---------------- compose: C[e][o][d] = sum_j head_w[o][j]*expert_w[e][j][d] ----------------
__global__ __launch_bounds__(256) void k_compose(const float* __restrict__ ew,
                                                 const float* __restrict__ eb,
                                                 const float* __restrict__ hw,
                                                 float* __restrict__ C,
                                                 float* __restrict__ hb2) {
    __shared__ float shw[840];
    __shared__ float seb[672];
    const int e = blockIdx.x, tid = threadIdx.x;
    for (int i = tid; i < 840; i += 256) shw[i] = hw[i];
    for (int i = tid; i < 672; i += 256) seb[i] = eb[i];
    __syncthreads();
    for (int i = tid; i < 840; i += 256) {
        int o = i / 84, d = i % 84;
        float s = 0.f;
        for (int j = 0; j < 84; ++j)
            s = fmaf(shw[o * 84 + j], ew[((size_t)e * 84 + j) * 84 + d], s);
        C[e * 840 + i] = s;
    }
    if (tid < 10) {
        float s = 0.f;
        for (int j = 0; j < 84; ++j) s = fmaf(shw[tid * 84 + j], seb[e * 84 + j], s);
        hb2[e * 10 + tid] = s;
    }
}

// ---------------- fused fc1(MFMA)+fc2+gate+MoE+head (round-18 verbatim) ----------------
__global__ __launch_bounds__(512) void k_fc1tail(const float* __restrict__ p2,
                                                 const float* __restrict__ f1w,
                                                 const float* __restrict__ f1b,
                                                 const float* __restrict__ f2w,
                                                 const float* __restrict__ f2b,
                                                 const float* __restrict__ gw,
                                                 const float* __restrict__ Cw,
                                                 const float* __restrict__ hb2,
                                                 const float* __restrict__ headb,
                                                 float* __restrict__ out) {
    __shared__ __align__(16) float region[23872];
    __shared__ float sh1[7744];          // h1: [64][121]
    __shared__ float sfb[84];
    __shared__ int   sei[128];
    const int tid = threadIdx.x;
    const int n0 = blockIdx.x * 64;

    // ---------- phase 1: fc1 via MFMA ----------
    {
        uint* hplu = (uint*)region;
        const int lane = tid & 63;
        const int wvv  = tid >> 6;
        const int cc = lane & 15, g = lane >> 4;
        const int outg = wvv * 16 + cc;
        f32x4 acc[4] = {{0.f,0.f,0.f,0.f},{0.f,0.f,0.f,0.f},{0.f,0.f,0.f,0.f},{0.f,0.f,0.f,0.f}};

        for (int kc = 0; kc < 4; ++kc) {
            __syncthreads();
            for (int p = tid; p < 4096; p += 512) {
                int row = p >> 6, pk = (p & 63) * 2;
                int k = kc * 128 + pk;
                float vx = 0.f, vy = 0.f;
                if (k < 400) {
                    float2 v = *(const float2*)(p2 + (size_t)(n0 + row) * 400 + k);
                    vx = v.x; vy = v.y;
                }
                _Float16 h0 = (_Float16)vx, h1 = (_Float16)vy;
                _Float16 l0 = (_Float16)(vx - (float)h0), l1 = (_Float16)(vy - (float)h1);
                hplu[row * 68 + (pk >> 1)]        = packhh(h0, h1);
                hplu[4352 + row * 68 + (pk >> 1)] = packhh(l0, l1);
            }
            __syncthreads();
            const int nslice = (kc < 3) ? 4 : 1;
            for (int s = 0; s < nslice; ++s) {
                const int kbase = kc * 128 + s * 32 + g * 8;
                float fa[8] = {0.f,0.f,0.f,0.f,0.f,0.f,0.f,0.f};
                if (outg < 120 && kbase + 7 < 400) {
                    float4 va = *(const float4*)(f1w + (size_t)outg * 400 + kbase);
                    float4 vb = *(const float4*)(f1w + (size_t)outg * 400 + kbase + 4);
                    fa[0]=va.x; fa[1]=va.y; fa[2]=va.z; fa[3]=va.w;
                    fa[4]=vb.x; fa[5]=vb.y; fa[6]=vb.z; fa[7]=vb.w;
                }
                half8 ah, al;
                #pragma unroll
                for (int j = 0; j < 8; ++j) {
                    _Float16 h = (_Float16)fa[j];
                    ah[j] = h;
                    al[j] = (_Float16)(fa[j] - (float)h);
                }
                #pragma unroll
                for (int nt = 0; nt < 4; ++nt) {
                    const int row = nt * 16 + cc;
                    uint4 hv = *(const uint4*)(hplu + row * 68 + s * 16 + g * 4);
                    uint4 lv = *(const uint4*)(hplu + 4352 + row * 68 + s * 16 + g * 4);
                    half8 bh8 = __builtin_bit_cast(half8, hv);
                    half8 bl8 = __builtin_bit_cast(half8, lv);
                    acc[nt] = __builtin_amdgcn_mfma_f32_16x16x32_f16(ah, bh8, acc[nt], 0, 0, 0);
                    acc[nt] = __builtin_amdgcn_mfma_f32_16x16x32_f16(ah, bl8, acc[nt], 0, 0, 0);
                    acc[nt] = __builtin_amdgcn_mfma_f32_16x16x32_f16(al, bh8, acc[nt], 0, 0, 0);
                }
            }
        }
        __syncthreads();
        float bo[4]; int ov[4];
        #pragma unroll
        for (int i2 = 0; i2 < 4; ++i2) {
            ov[i2] = wvv * 16 + g * 4 + i2;
            bo[i2] = (ov[i2] < 120) ? f1b[ov[i2]] : 0.f;
        }
        #pragma unroll
        for (int nt = 0; nt < 4; ++nt) {
            const int token = nt * 16 + cc;
            #pragma unroll
            for (int i2 = 0; i2 < 4; ++i2) {
                if (ov[i2] < 120)
                    sh1[token * 121 + ov[i2]] = fmaxf(acc[nt][i2] + bo[i2], 0.f);
            }
        }
    }

    // ---------- phase 2: fc2 + gate + top2 + MoE + head ----------
    float* sfw  = region;
    float* sC   = region + 10164;
    float* sh   = region + 16964;
    float* sgw  = region + 22404;
    float* shb2s= region + 23076;
    float* shb  = region + 23156;
    float* slog = region + 23168;
    float* swt2 = region + 23744;

    for (int i = tid; i < 2520; i += 512) {
        int o = i / 30, k4 = (i % 30) * 4;
        float4 v = *(const float4*)(f2w + (size_t)o * 120 + k4);
        float* d = sfw + o * 121 + k4;
        d[0] = v.x; d[1] = v.y; d[2] = v.z; d[3] = v.w;
    }
    for (int i = tid; i < 6720; i += 512) sC[(i / 84) * 85 + (i % 84)] = Cw[i];
    for (int i = tid; i < 672; i += 512) sgw[i] = gw[i];
    if (tid < 80) shb2s[tid] = hb2[tid];
    if (tid < 10) shb[tid] = headb[tid];
    if (tid < 84) sfb[tid] = f2b[tid];
    __syncthreads();

    for (int i = tid; i < 5376; i += 512) {
        const int t = i / 84, o = i % 84;
        const float* a = sh1 + t * 121;
        const float* wr = sfw + o * 121;
        float s = 0.f;
        #pragma unroll 8
        for (int k = 0; k < 120; ++k) s = fmaf(a[k], wr[k], s);
        sh[t * 85 + o] = fmaxf(s + sfb[o], 0.f);
    }
    __syncthreads();

    {
        const int t = tid / 8, e = tid % 8;
        const float* a = sh + t * 85;
        float s = 0.f;
        #pragma unroll 4
        for (int d = 0; d < 84; ++d) s = fmaf(a[d], sgw[d * 8 + e], s);
        slog[t * 9 + e] = s;
    }
    __syncthreads();

    if (tid < 64) {
        const float* l = slog + tid * 9;
        float m1 = l[0]; int i1 = 0;
        #pragma unroll
        for (int e = 1; e < 8; ++e) if (l[e] > m1) { m1 = l[e]; i1 = e; }
        float m2 = -1e30f; int i2 = 0;
        #pragma unroll
        for (int e = 0; e < 8; ++e) if (e != i1 && l[e] > m2) { m2 = l[e]; i2 = e; }
        const float r = expf(m2 - m1);
        const float inv = 1.f / (1.f + r);
        swt2[tid * 2] = inv; swt2[tid * 2 + 1] = r * inv;
        sei[tid * 2] = i1; sei[tid * 2 + 1] = i2;
    }
    __syncthreads();

    for (int i = tid; i < 640; i += 512) {
        const int t = i / 10, o = i % 10;
        const float* a = sh + t * 85;
        const float w0 = swt2[t * 2], w1 = swt2[t * 2 + 1];
        const int e0 = sei[t * 2], e1 = sei[t * 2 + 1];
        const float* c0 = sC + (e0 * 10 + o) * 85;
        const float* c1 = sC + (e1 * 10 + o) * 85;
        float s0 = 0.f, s1 = 0.f;
        #pragma unroll 4
        for (int d = 0; d < 84; ++d) {
            s0 = fmaf(a[d], c0[d], s0);
            s1 = fmaf(a[d], c1[d], s1);
        }
        out[(size_t)(n0 + t) * 10 + o] =
            shb[o] + w0 * (s0 + shb2s[e0 * 10 + o]) + w1 * (s1 + shb2s[e1 * 10 + o]);
    }
}

extern "C" void kernel_launch(void* const* d_in, const int* in_sizes, int n_in,
                              void* d_out, int out_size, void* d_ws, size_t ws_size,
                              hipStream_t stream) {
    const float* x   = (const float*)d_in[0];
    const float* c1w = (const float*)d_in[1];
    const float* c1b = (const float*)d_in[2];
    const float* c2w = (const float*)d_in[3];
    const float* c2b = (const float*)d_in[4];
    const float* f1w = (const float*)d_in[5];
    const float* f1b = (const float*)d_in[6];
    const float* f2w = (const float*)d_in[7];
    const float* f2b = (const float*)d_in[8];
    const float* gw  = (const float*)d_in[9];
    const float* ew  = (const float*)d_in[10];
    const float* eb  = (const float*)d_in[11];
    const float* hw  = (const float*)d_in[12];
    const float* hb  = (const float*)d_in[13];
    float* out = (float*)d_out;

    const int N = in_sizes[0] / 3072;   // 16384

    float* ws = (float*)d_ws;
    uint*  p1  = (uint*)ws;                    // N*1176 uints (compact packed hi/lo)
    float* p2  = ws + (size_t)N * 1176;        // N*400
    float* C   = p2 + (size_t)N * 400;         // 6720
    float* hb2 = C + 6720;                     // 80

    k_conv1<<<N / 2, 256, 0, stream>>>(x, c1w, c1b, p1);
    k_conv2<<<N / 4, 256, 0, stream>>>(p1, c2w, c2b, p2);
    k_compose<<<8, 256, 0, stream>>>(ew, eb, hw, C, hb2);
    k_fc1tail<<<N / 64, 512, 0, stream>>>(p2, f1w, f1b, f2w, f2b, gw, C, hb2, hb, out);
}